// Round 9
// baseline (7015.240 us; speedup 1.0000x reference)
//
#include <hip/hip_runtime.h>
#include <hip/hip_fp16.h>

#define TPB 256
#define SCB 256
#define SCI 16   // scan items per thread -> 4096 per block

__device__ __forceinline__ float wred_max(float v) {
    #pragma unroll
    for (int o = 32; o >= 1; o >>= 1) v = fmaxf(v, __shfl_xor(v, o));
    return v;
}
__device__ __forceinline__ float wred_sum(float v) {
    #pragma unroll
    for (int o = 32; o >= 1; o >>= 1) v += __shfl_xor(v, o);
    return v;
}
__device__ __forceinline__ float h2f_u16(unsigned short u) {
    __half_raw r; r.x = u; return __half2float(__half(r));
}
__device__ __forceinline__ float h2f_lo(unsigned u) { return h2f_u16((unsigned short)(u & 0xffffu)); }
__device__ __forceinline__ float h2f_hi(unsigned u) { return h2f_u16((unsigned short)(u >> 16)); }
__device__ __forceinline__ unsigned f2h_pack(float a, float b) {
    __half ha = __float2half(a), hb = __float2half(b);
    __half_raw ra = *(__half_raw*)&ha, rb = *(__half_raw*)&hb;
    return (unsigned)ra.x | ((unsigned)rb.x << 16);
}

// ---------------- node featurizer: wave per node (coalesced x reads) ----------------
__global__ void k_node(const float* __restrict__ x, const float* __restrict__ emb,
                       const float* __restrict__ nw, const float* __restrict__ nbv,
                       float* __restrict__ h, int N, int XW, int NA) {
    __shared__ float s_w[24 * 17];
    __shared__ float s_b[24];
    __shared__ float sF[4][20];
    for (int t = threadIdx.x; t < 24 * 17; t += blockDim.x) s_w[t] = nw[t];
    for (int t = threadIdx.x; t < 24; t += blockDim.x) s_b[t] = nbv[t];
    __syncthreads();
    int wid = threadIdx.x >> 6, lane = threadIdx.x & 63;
    int n = blockIdx.x * 4 + wid;
    if (n >= N) return;
    const float* row = x + (size_t)n * XW;
    // argmax over cols [0, NA) ; NA <= 128
    float v0 = (lane < NA) ? row[lane] : -3.4e38f;
    float v1 = (lane + 64 < NA) ? row[lane + 64] : -3.4e38f;
    float bv; int bi;
    if (v1 > v0) { bv = v1; bi = lane + 64; } else { bv = v0; bi = lane; }
    #pragma unroll
    for (int o = 32; o >= 1; o >>= 1) {
        float ov = __shfl_xor(bv, o); int oi = __shfl_xor(bi, o);
        if (ov > bv || (ov == bv && oi < bi)) { bv = ov; bi = oi; }
    }
    if (lane < 16) sF[wid][lane] = emb[(size_t)bi * 16 + lane];
    if (lane == 16) sF[wid][16] = row[XW - 1];
    if (lane < 24) {
        float a = s_b[lane];
        #pragma unroll
        for (int j = 0; j < 17; ++j) a = fmaf(s_w[lane * 17 + j], sF[wid][j], a);
        h[(size_t)n * 24 + lane] = a;
    }
}

// ---------------- CSR build, bucketed by (dst, src-tile) ----------------
__global__ void k_count(const int* __restrict__ ei, int* __restrict__ cnt,
                        int E2, int NT, int tshift) {
    int e = blockIdx.x * blockDim.x + threadIdx.x;
    if (e >= E2) return;
    int s = ei[e];
    int d = ei[E2 + e];
    atomicAdd(&cnt[(size_t)d * NT + (s >> tshift)], 1);
}

__global__ void k_scan_bsum(const int* __restrict__ indeg, int* __restrict__ bsum, int M) {
    int base = blockIdx.x * SCB * SCI;
    int t = threadIdx.x;
    int s = 0;
    #pragma unroll
    for (int i = 0; i < SCI; ++i) {
        int idx = base + t * SCI + i;
        if (idx < M) s += indeg[idx];
    }
    #pragma unroll
    for (int o = 32; o >= 1; o >>= 1) s += __shfl_xor(s, o);
    __shared__ int red[SCB / 64];
    if ((t & 63) == 0) red[t >> 6] = s;
    __syncthreads();
    if (t == 0) {
        int tot = 0;
        for (int w = 0; w < SCB / 64; ++w) tot += red[w];
        bsum[blockIdx.x] = tot;
    }
}

__global__ void k_scan_final(const int* __restrict__ indeg, const int* __restrict__ bsum,
                             int* __restrict__ rowptr, int M, int nb) {
    __shared__ int s_t[SCB];
    __shared__ int s_boff;
    int base = blockIdx.x * SCB * SCI;
    int t = threadIdx.x;
    if (t == 0) {
        int off = 0;
        for (int i = 0; i < (int)blockIdx.x; ++i) off += bsum[i];
        s_boff = off;
        if (blockIdx.x == 0) {
            int tot = 0;
            for (int i = 0; i < nb; ++i) tot += bsum[i];
            rowptr[M] = tot;
        }
    }
    int loc[SCI]; int s = 0;
    #pragma unroll
    for (int i = 0; i < SCI; ++i) {
        int idx = base + t * SCI + i;
        int v = (idx < M) ? indeg[idx] : 0;
        loc[i] = s; s += v;
    }
    s_t[t] = s;
    __syncthreads();
    for (int o = 1; o < SCB; o <<= 1) {
        int v = (t >= o) ? s_t[t - o] : 0;
        __syncthreads();
        s_t[t] += v;
        __syncthreads();
    }
    int toff = ((t > 0) ? s_t[t - 1] : 0) + s_boff;
    #pragma unroll
    for (int i = 0; i < SCI; ++i) {
        int idx = base + t * SCI + i;
        if (idx < M) rowptr[idx] = toff + loc[i];
    }
}

__global__ void k_cursor(const int* __restrict__ rowptr, int* __restrict__ cursor, int M) {
    int i = blockIdx.x * blockDim.x + threadIdx.x;
    if (i < M) cursor[i] = rowptr[i];
}

__global__ void k_scatter(const int* __restrict__ ei, int* __restrict__ cursor,
                          int* __restrict__ csr_src, int* __restrict__ csr_aid,
                          unsigned long long* __restrict__ att16, const float* __restrict__ attr,
                          int E2, int EU, int NT, int tshift, int dup16) {
    int e = blockIdx.x * blockDim.x + threadIdx.x;
    if (e >= E2) return;
    int s = ei[e];
    int d = ei[E2 + e];
    int pos = atomicAdd(&cursor[(size_t)d * NT + (s >> tshift)], 1);
    csr_src[pos] = s;
    int aid = (e < EU) ? e : e - EU;
    csr_aid[pos] = aid;
    if (dup16) {
        float4 av = *(const float4*)(attr + (size_t)aid * 4);
        unsigned lo = f2h_pack(av.x, av.y), hi = f2h_pack(av.z, av.w);
        att16[pos] = (unsigned long long)lo | ((unsigned long long)hi << 32);
    }
}

// ---------------- per-node raw-attr sums (for self-loop mean), once per call ---------
__global__ void k_asum(const int* __restrict__ rowptrT, int NT,
                       const unsigned long long* __restrict__ att16,
                       const int* __restrict__ csr_aid, const float* __restrict__ attr,
                       float* __restrict__ slsum, int N) {
    int wid = threadIdx.x >> 6, lane = threadIdx.x & 63;
    int n = blockIdx.x * 4 + wid;
    if (n >= N) return;
    int rb = rowptrT[(size_t)n * NT], re = rowptrT[(size_t)(n + 1) * NT];
    float s0 = 0.f, s1 = 0.f, s2 = 0.f, s3 = 0.f;
    for (int j = rb + lane; j < re; j += 64) {
        if (att16) {
            unsigned long long au = __builtin_nontemporal_load(att16 + j);
            unsigned lo = (unsigned)au, hi = (unsigned)(au >> 32);
            s0 += h2f_lo(lo); s1 += h2f_hi(lo); s2 += h2f_lo(hi); s3 += h2f_hi(hi);
        } else {
            int aid = csr_aid[j];
            float4 av = *(const float4*)(attr + (size_t)aid * 4);
            s0 += av.x; s1 += av.y; s2 += av.z; s3 += av.w;
        }
    }
    s0 = wred_sum(s0); s1 = wred_sum(s1); s2 = wred_sum(s2); s3 = wred_sum(s3);
    if (lane == 0) {
        slsum[(size_t)n * 4 + 0] = s0; slsum[(size_t)n * 4 + 1] = s1;
        slsum[(size_t)n * 4 + 2] = s2; slsum[(size_t)n * 4 + 3] = s3;
    }
}

// ---------------- per-node left/right transforms (both fp32) ----------------
template <int IN, int OUT>
__global__ void k_xform(const float* __restrict__ h,
                        const float* __restrict__ wl, const float* __restrict__ bl,
                        const float* __restrict__ wr, const float* __restrict__ br,
                        float* __restrict__ xl, float* __restrict__ xr, int N) {
    __shared__ float s_wl[OUT * IN], s_wr[OUT * IN], s_bl[OUT], s_br[OUT];
    for (int t = threadIdx.x; t < OUT * IN; t += blockDim.x) { s_wl[t] = wl[t]; s_wr[t] = wr[t]; }
    for (int t = threadIdx.x; t < OUT; t += blockDim.x) { s_bl[t] = bl[t]; s_br[t] = br[t]; }
    __syncthreads();
    int n = blockIdx.x * blockDim.x + threadIdx.x;
    if (n >= N) return;
    float f[IN];
    const float* hr = h + (size_t)n * IN;
    #pragma unroll
    for (int j = 0; j < IN; ++j) f[j] = hr[j];
    float* xlr = xl + (size_t)n * OUT;
    float* xrr = xr + (size_t)n * OUT;
    #pragma unroll
    for (int k = 0; k < OUT; ++k) {
        float al = s_bl[k], ar = s_br[k];
        #pragma unroll
        for (int j = 0; j < IN; ++j) {
            al = fmaf(s_wl[k * IN + j], f[j], al);
            ar = fmaf(s_wr[k * IN + j], f[j], ar);
        }
        xlr[k] = al; xrr[k] = ar;
    }
}

// ---------------- fused GATv2, src-tiled multi-pass ----------------
// Pass tpass processes only edges whose src is in tile tpass (CSR bucketed by
// (dst, src-tile)), so the concurrent gather working set is one ~4MB xl tile ->
// per-XCD L2 hits. Online-softmax state (m, den, acc) is carried across passes in
// global memory (Sacc aliases h; only one of Sacc/h is touched per instantiation).
// Streaming data uses nontemporal loads/stores so L2 stays reserved for xl.
// Inner structure identical to the verified round-7 kernel (streamed fp32 gather,
// channel-major 65-stride LDS, all-lane LDS p-broadcast).
template <int OUT, int MINW, bool FIRST, bool FINAL>
__launch_bounds__(256, MINW)
__global__ void k_gat(const int* __restrict__ rowptrT, int NT, int tpass,
                      const int* __restrict__ csr_src, const int* __restrict__ csr_aid,
                      const unsigned long long* __restrict__ att16, const float* __restrict__ attr,
                      const float* __restrict__ xl, const float* __restrict__ xr,
                      const float* __restrict__ slsum,
                      float* __restrict__ Sm, float* __restrict__ Sden, float* __restrict__ Sacc,
                      const float* __restrict__ we, const float* __restrict__ ew,
                      const float* __restrict__ eb, const float* __restrict__ att,
                      const float* __restrict__ bias, float* __restrict__ h, int N) {
    __shared__ float sC[OUT * 4], sCb[OUT], sAtt[OUT], sB[OUT];
    __shared__ float sXB[4][OUT];        // xr row + sCb, per wave
    __shared__ float sXL[4][OUT * 65];   // staged rows, channel-major, stride 65 = conflict-free
    __shared__ float sP[4][64];          // per-wave p broadcast (all-lane write)
    // fold edge MLP into GAT edge projection: C = we @ edge_w (OUT x 4), cb = we @ edge_b
    for (int t = threadIdx.x; t < OUT * 5; t += blockDim.x) {
        int k = t / 5, c = t - k * 5;
        float a = 0.f;
        if (c < 4) { for (int j = 0; j < 12; ++j) a += we[k * 12 + j] * ew[j * 4 + c]; sC[k * 4 + c] = a; }
        else       { for (int j = 0; j < 12; ++j) a += we[k * 12 + j] * eb[j];          sCb[k] = a; }
    }
    for (int t = threadIdx.x; t < OUT; t += blockDim.x) { sAtt[t] = att[t]; sB[t] = bias[t]; }
    __syncthreads();

    int wid = threadIdx.x >> 6, lane = threadIdx.x & 63;
    int n = blockIdx.x * 4 + wid;
    if (n >= N) return;   // wave-uniform; no syncthreads after this point

    size_t rbase = (size_t)n * NT + tpass;
    int rb = __builtin_nontemporal_load(rowptrT + rbase);
    int re = __builtin_nontemporal_load(rowptrT + rbase + 1);
    if (!FIRST && !FINAL && rb == re) return;   // state unchanged, skip RMW

    if (lane < OUT)
        sXB[wid][lane] = __builtin_nontemporal_load(xr + (size_t)n * OUT + lane) + sCb[lane];

    float* myXL = &sXL[wid][0];
    float* myP  = &sP[wid][0];

    float m, den, acc;
    if (FIRST) { m = -INFINITY; den = 0.f; acc = 0.f; }
    else {
        m   = __builtin_nontemporal_load(Sm + n);
        den = __builtin_nontemporal_load(Sden + n);
        acc = (lane < OUT) ? __builtin_nontemporal_load(Sacc + (size_t)n * OUT + lane) : 0.f;
    }

    for (int c0 = rb; c0 < re; c0 += 64) {
        int j = c0 + lane;
        float lg = -INFINITY;
        if (j < re) {
            int s = __builtin_nontemporal_load(csr_src + j);
            float ax, ay, az, aw;
            if (att16) {
                unsigned long long au = __builtin_nontemporal_load(att16 + j);
                unsigned lo = (unsigned)au, hi = (unsigned)(au >> 32);
                ax = h2f_lo(lo); ay = h2f_hi(lo); az = h2f_lo(hi); aw = h2f_hi(hi);
            } else {
                int aid = __builtin_nontemporal_load(csr_aid + j);
                float4 av = *(const float4*)(attr + (size_t)aid * 4);
                ax = av.x; ay = av.y; az = av.z; aw = av.w;
            }
            const float4* xs4 = (const float4*)(xl + (size_t)s * OUT);   // cacheable: the tile
            lg = 0.f;
            #pragma unroll
            for (int q4 = 0; q4 < OUT / 4; ++q4) {
                float4 v = xs4[q4];
                myXL[(4 * q4 + 0) * 65 + lane] = v.x;
                myXL[(4 * q4 + 1) * 65 + lane] = v.y;
                myXL[(4 * q4 + 2) * 65 + lane] = v.z;
                myXL[(4 * q4 + 3) * 65 + lane] = v.w;
                #pragma unroll
                for (int r = 0; r < 4; ++r) {
                    int k = 4 * q4 + r;
                    float xlv = (r == 0) ? v.x : (r == 1) ? v.y : (r == 2) ? v.z : v.w;
                    float c = sXB[wid][k];
                    c = fmaf(sC[k * 4 + 0], ax, c);
                    c = fmaf(sC[k * 4 + 1], ay, c);
                    c = fmaf(sC[k * 4 + 2], az, c);
                    c = fmaf(sC[k * 4 + 3], aw, c);
                    float mm = xlv + c;
                    float lr = (mm > 0.f) ? mm : 0.2f * mm;
                    lg = fmaf(sAtt[k], lr, lg);
                }
            }
        }
        float cm = wred_max(lg);
        float nm = fmaxf(m, cm);
        float sc = __expf(m - nm);          // m=-inf on first-ever chunk -> 0
        float p = (j < re) ? __expf(lg - nm) : 0.f;
        myP[lane] = p;                      // ALL 64 lanes write (convergent)
        float ps = wred_sum(p);
        den = den * sc + ps;
        m = nm;
        int cntc = min(64, re - c0);
        if (lane < OUT) {
            float a0 = 0.f, a1 = 0.f, a2 = 0.f, a3 = 0.f;
            int t = 0;
            for (; t + 3 < cntc; t += 4) {
                a0 = fmaf(myP[t],     myXL[lane * 65 + t],     a0);
                a1 = fmaf(myP[t + 1], myXL[lane * 65 + t + 1], a1);
                a2 = fmaf(myP[t + 2], myXL[lane * 65 + t + 2], a2);
                a3 = fmaf(myP[t + 3], myXL[lane * 65 + t + 3], a3);
            }
            for (; t < cntc; ++t) a0 = fmaf(myP[t], myXL[lane * 65 + t], a0);
            acc = fmaf(acc, sc, (a0 + a1) + (a2 + a3));
        }
    }

    if (!FINAL) {
        if (lane == 0) {
            __builtin_nontemporal_store(m, Sm + n);
            __builtin_nontemporal_store(den, Sden + n);
        }
        if (lane < OUT) __builtin_nontemporal_store(acc, Sacc + (size_t)n * OUT + lane);
        return;
    }

    // FINAL pass: self-loop (attr = mean of incoming attrs; exact-0 if indeg==0) + finish
    int rb0 = __builtin_nontemporal_load(rowptrT + (size_t)n * NT);
    int reN = __builtin_nontemporal_load(rowptrT + (size_t)(n + 1) * NT);
    int cnt = reN - rb0;
    float inv = (cnt > 0) ? 1.f / (float)cnt : 0.f;
    float a0 = __builtin_nontemporal_load(slsum + (size_t)n * 4 + 0) * inv;
    float a1 = __builtin_nontemporal_load(slsum + (size_t)n * 4 + 1) * inv;
    float a2 = __builtin_nontemporal_load(slsum + (size_t)n * 4 + 2) * inv;
    float a3 = __builtin_nontemporal_load(slsum + (size_t)n * 4 + 3) * inv;

    float xln = 0.f, contrib = 0.f;
    if (lane < OUT) {
        xln = xl[(size_t)n * OUT + lane];
        float dot = 0.f;
        dot = fmaf(sC[lane * 4 + 0], a0, dot);
        dot = fmaf(sC[lane * 4 + 1], a1, dot);
        dot = fmaf(sC[lane * 4 + 2], a2, dot);
        dot = fmaf(sC[lane * 4 + 3], a3, dot);
        // sXB = xr + sCb; when indeg==0 the transformed self attr is 0 -> remove sCb
        float mm = xln + sXB[wid][lane] + ((cnt > 0) ? dot : -sCb[lane]);
        float lr = (mm > 0.f) ? mm : 0.2f * mm;
        contrib = sAtt[lane] * lr;
    }
    float lgs = wred_sum(contrib);
    float nm = fmaxf(m, lgs);
    float sc = __expf(m - nm);
    float p = __expf(lgs - nm);
    den = den * sc + p;                      // den >= p > 0: no div-by-zero
    if (lane < OUT) {
        acc = acc * sc + p * xln;
        float v = acc / den + sB[lane];
        __builtin_nontemporal_store((v > 0.f) ? v : 0.f, h + (size_t)n * OUT + lane);
    }
}

// ---------------- mean pool: one block per graph, batch is sorted ----------------
__global__ void k_pool(const float* __restrict__ h, const int* __restrict__ batch,
                       float* __restrict__ pmean, int N) {
    int g = blockIdx.x;
    int a = 0, b = N;
    while (a < b) { int mid = (a + b) >> 1; if (batch[mid] < g) a = mid + 1; else b = mid; }
    int lo = a;
    a = lo; b = N;
    while (a < b) { int mid = (a + b) >> 1; if (batch[mid] < g + 1) a = mid + 1; else b = mid; }
    int hi = a;
    int cnt = hi - lo;
    int wid = threadIdx.x >> 6, lane = threadIdx.x & 63;
    float acc = 0.f;
    if (lane < 36) {
        for (int n = lo + wid; n < hi; n += 4) acc += h[(size_t)n * 36 + lane];
    }
    __shared__ float s_acc[4][36];
    if (lane < 36) s_acc[wid][lane] = acc;
    __syncthreads();
    if (threadIdx.x < 36) {
        float v = s_acc[0][threadIdx.x] + s_acc[1][threadIdx.x] +
                  s_acc[2][threadIdx.x] + s_acc[3][threadIdx.x];
        float iv = (cnt > 0) ? 1.f / (float)cnt : 0.f;
        pmean[(size_t)g * 36 + threadIdx.x] = v * iv;
    }
}

// ---------------- final head ----------------
__global__ void k_final(const float* __restrict__ pmean,
                        const float* __restrict__ fw, const float* __restrict__ fb,
                        float* __restrict__ out, int G) {
    int t = blockIdx.x * blockDim.x + threadIdx.x;
    if (t >= G * 64) return;
    int g = t / 64, o = t - g * 64;
    float a = fb[o];
    #pragma unroll
    for (int k = 0; k < 36; ++k) a = fmaf(pmean[(size_t)g * 36 + k], fw[o * 36 + k], a);
    out[t] = a;
}

extern "C" void kernel_launch(void* const* d_in, const int* in_sizes, int n_in,
                              void* d_out, int out_size, void* d_ws, size_t ws_size,
                              hipStream_t stream) {
    const float* x      = (const float*)d_in[0];
    const int*   ei     = (const int*)d_in[1];
    const float* eattr  = (const float*)d_in[2];
    const int*   batch  = (const int*)d_in[3];
    const float* emb    = (const float*)d_in[4];
    const float* node_w = (const float*)d_in[5];
    const float* node_b = (const float*)d_in[6];
    const float* edge_w = (const float*)d_in[7];
    const float* edge_b = (const float*)d_in[8];
    const float* c1_wl  = (const float*)d_in[9];
    const float* c1_bl  = (const float*)d_in[10];
    const float* c1_wr  = (const float*)d_in[11];
    const float* c1_br  = (const float*)d_in[12];
    const float* c1_we  = (const float*)d_in[13];
    const float* c1_att = (const float*)d_in[14];
    const float* c1_bias= (const float*)d_in[15];
    const float* c2_wl  = (const float*)d_in[16];
    const float* c2_bl  = (const float*)d_in[17];
    const float* c2_wr  = (const float*)d_in[18];
    const float* c2_br  = (const float*)d_in[19];
    const float* c2_we  = (const float*)d_in[20];
    const float* c2_att = (const float*)d_in[21];
    const float* c2_bias= (const float*)d_in[22];
    const float* fin_w  = (const float*)d_in[23];
    const float* fin_b  = (const float*)d_in[24];
    float* out = (float*)d_out;

    const int N  = in_sizes[3];
    const int E2 = in_sizes[1] / 2;
    const int EU = in_sizes[2] / 4;
    const int XW = in_sizes[0] / N;
    const int NA = in_sizes[4] / 16;
    const int G  = out_size / 64;

    // choose NT (src tiles) and att16 use per available workspace
    auto need = [&](int nt, int a16) -> size_t {
        size_t o = (size_t)N * (36 * 3 + 4 + 1 + 1) + (size_t)G * 36 + 256
                 + ((size_t)N * nt + 1) + (size_t)N * nt + 2 * (size_t)E2;
        if (a16) { o = (o + 1) & ~(size_t)1; o += (size_t)E2 * 2; }
        return o * 4;
    };
    int NT, use16;
    if      (ws_size >= need(4, 1)) { NT = 4; use16 = 1; }
    else if (ws_size >= need(4, 0)) { NT = 4; use16 = 0; }
    else if (ws_size >= need(1, 1)) { NT = 1; use16 = 1; }
    else if (ws_size >= need(1, 0)) { NT = 1; use16 = 0; }
    else return;  // loud failure: output stays poisoned

    int tshift = 30;
    if (NT > 1) { tshift = 0; while (((N - 1) >> tshift) >= NT) tshift++; }
    const int M = N * NT;

    // workspace layout (4B units)
    float* ws = (float*)d_ws;
    size_t off = 0;
    float* h      = ws + off;              off += (size_t)N * 36;   // also Sacc (aliased)
    float* xl     = ws + off;              off += (size_t)N * 36;
    float* xr     = ws + off;              off += (size_t)N * 36;
    float* pmean  = ws + off;              off += (size_t)G * 36;
    float* slsum  = ws + off;              off += (size_t)N * 4;
    float* Sm     = ws + off;              off += (size_t)N;
    float* Sden   = ws + off;              off += (size_t)N;
    int*   bsum   = (int*)(ws + off);      off += 256;
    int*   rowptrT= (int*)(ws + off);      off += (size_t)M + 1;
    int*   cursor = (int*)(ws + off);      off += (size_t)M;
    int*   csr_src= (int*)(ws + off);      off += (size_t)E2;
    int*   csr_aid= (int*)(ws + off);      off += (size_t)E2;
    off = (off + 1) & ~(size_t)1;
    unsigned long long* att16 = (unsigned long long*)(ws + off);
    unsigned long long* att16_k = use16 ? att16 : (unsigned long long*)nullptr;

    hipMemsetAsync(cursor, 0, (size_t)M * 4, stream);

    dim3 b(TPB);
    dim3 gN((N + TPB - 1) / TPB);
    dim3 gE((E2 + TPB - 1) / TPB);
    dim3 gW((N + 3) / 4);   // 4 waves per block, 1 wave per node
    dim3 gM((M + TPB - 1) / TPB);
    int nb = (M + SCB * SCI - 1) / (SCB * SCI);

    k_node<<<gW, b, 0, stream>>>(x, emb, node_w, node_b, h, N, XW, NA);
    k_count<<<gE, b, 0, stream>>>(ei, cursor, E2, NT, tshift);
    k_scan_bsum<<<nb, SCB, 0, stream>>>(cursor, bsum, M);
    k_scan_final<<<nb, SCB, 0, stream>>>(cursor, bsum, rowptrT, M, nb);
    k_cursor<<<gM, b, 0, stream>>>(rowptrT, cursor, M);
    k_scatter<<<gE, b, 0, stream>>>(ei, cursor, csr_src, csr_aid, att16, eattr,
                                    E2, EU, NT, tshift, use16);
    k_asum<<<gW, b, 0, stream>>>(rowptrT, NT, att16_k, csr_aid, eattr, slsum, N);

    // ---- layer 1 (24 -> 24), MINW=6 ----
    k_xform<24, 24><<<gN, b, 0, stream>>>(h, c1_wl, c1_bl, c1_wr, c1_br, xl, xr, N);
    if (NT == 4) {
        k_gat<24, 6, true,  false><<<gW, b, 0, stream>>>(rowptrT, NT, 0, csr_src, csr_aid, att16_k, eattr, xl, xr, slsum, Sm, Sden, h, c1_we, edge_w, edge_b, c1_att, c1_bias, h, N);
        k_gat<24, 6, false, false><<<gW, b, 0, stream>>>(rowptrT, NT, 1, csr_src, csr_aid, att16_k, eattr, xl, xr, slsum, Sm, Sden, h, c1_we, edge_w, edge_b, c1_att, c1_bias, h, N);
        k_gat<24, 6, false, false><<<gW, b, 0, stream>>>(rowptrT, NT, 2, csr_src, csr_aid, att16_k, eattr, xl, xr, slsum, Sm, Sden, h, c1_we, edge_w, edge_b, c1_att, c1_bias, h, N);
        k_gat<24, 6, false, true ><<<gW, b, 0, stream>>>(rowptrT, NT, 3, csr_src, csr_aid, att16_k, eattr, xl, xr, slsum, Sm, Sden, h, c1_we, edge_w, edge_b, c1_att, c1_bias, h, N);
    } else {
        k_gat<24, 6, true,  true ><<<gW, b, 0, stream>>>(rowptrT, NT, 0, csr_src, csr_aid, att16_k, eattr, xl, xr, slsum, Sm, Sden, h, c1_we, edge_w, edge_b, c1_att, c1_bias, h, N);
    }

    // ---- layer 2 (24 -> 36), MINW=4 ----
    k_xform<24, 36><<<gN, b, 0, stream>>>(h, c2_wl, c2_bl, c2_wr, c2_br, xl, xr, N);
    if (NT == 4) {
        k_gat<36, 4, true,  false><<<gW, b, 0, stream>>>(rowptrT, NT, 0, csr_src, csr_aid, att16_k, eattr, xl, xr, slsum, Sm, Sden, h, c2_we, edge_w, edge_b, c2_att, c2_bias, h, N);
        k_gat<36, 4, false, false><<<gW, b, 0, stream>>>(rowptrT, NT, 1, csr_src, csr_aid, att16_k, eattr, xl, xr, slsum, Sm, Sden, h, c2_we, edge_w, edge_b, c2_att, c2_bias, h, N);
        k_gat<36, 4, false, false><<<gW, b, 0, stream>>>(rowptrT, NT, 2, csr_src, csr_aid, att16_k, eattr, xl, xr, slsum, Sm, Sden, h, c2_we, edge_w, edge_b, c2_att, c2_bias, h, N);
        k_gat<36, 4, false, true ><<<gW, b, 0, stream>>>(rowptrT, NT, 3, csr_src, csr_aid, att16_k, eattr, xl, xr, slsum, Sm, Sden, h, c2_we, edge_w, edge_b, c2_att, c2_bias, h, N);
    } else {
        k_gat<36, 4, true,  true ><<<gW, b, 0, stream>>>(rowptrT, NT, 0, csr_src, csr_aid, att16_k, eattr, xl, xr, slsum, Sm, Sden, h, c2_we, edge_w, edge_b, c2_att, c2_bias, h, N);
    }

    // ---- pool + head ----
    k_pool<<<G, b, 0, stream>>>(h, batch, pmean, N);
    k_final<<<(G * 64 + TPB - 1) / TPB, b, 0, stream>>>(pmean, fin_w, fin_b, out, G);
}

// Round 10
// 2485.635 us; speedup vs baseline: 2.8223x; 2.8223x over previous
//
#include <hip/hip_runtime.h>
#include <hip/hip_fp16.h>

#define TPB 256
#define SCB 256
#define SCI 16   // scan items per thread -> 4096 per block

__device__ __forceinline__ float wred_max(float v) {
    #pragma unroll
    for (int o = 32; o >= 1; o >>= 1) v = fmaxf(v, __shfl_xor(v, o));
    return v;
}
__device__ __forceinline__ float wred_sum(float v) {
    #pragma unroll
    for (int o = 32; o >= 1; o >>= 1) v += __shfl_xor(v, o);
    return v;
}
__device__ __forceinline__ float h2f_u16(unsigned short u) {
    __half_raw r; r.x = u; return __half2float(__half(r));
}
__device__ __forceinline__ float h2f_lo(unsigned u) { return h2f_u16((unsigned short)(u & 0xffffu)); }
__device__ __forceinline__ float h2f_hi(unsigned u) { return h2f_u16((unsigned short)(u >> 16)); }
__device__ __forceinline__ unsigned f2h_pack(float a, float b) {
    __half ha = __float2half(a), hb = __float2half(b);
    __half_raw ra = *(__half_raw*)&ha, rb = *(__half_raw*)&hb;
    return (unsigned)ra.x | ((unsigned)rb.x << 16);
}

// ---------------- node featurizer: wave per node (coalesced x reads) ----------------
__global__ void k_node(const float* __restrict__ x, const float* __restrict__ emb,
                       const float* __restrict__ nw, const float* __restrict__ nbv,
                       float* __restrict__ h, int N, int XW, int NA) {
    __shared__ float s_w[24 * 17];
    __shared__ float s_b[24];
    __shared__ float sF[4][20];
    for (int t = threadIdx.x; t < 24 * 17; t += blockDim.x) s_w[t] = nw[t];
    for (int t = threadIdx.x; t < 24; t += blockDim.x) s_b[t] = nbv[t];
    __syncthreads();
    int wid = threadIdx.x >> 6, lane = threadIdx.x & 63;
    int n = blockIdx.x * 4 + wid;
    if (n >= N) return;
    const float* row = x + (size_t)n * XW;
    float v0 = (lane < NA) ? row[lane] : -3.4e38f;
    float v1 = (lane + 64 < NA) ? row[lane + 64] : -3.4e38f;
    float bv; int bi;
    if (v1 > v0) { bv = v1; bi = lane + 64; } else { bv = v0; bi = lane; }
    #pragma unroll
    for (int o = 32; o >= 1; o >>= 1) {
        float ov = __shfl_xor(bv, o); int oi = __shfl_xor(bi, o);
        if (ov > bv || (ov == bv && oi < bi)) { bv = ov; bi = oi; }
    }
    if (lane < 16) sF[wid][lane] = emb[(size_t)bi * 16 + lane];
    if (lane == 16) sF[wid][16] = row[XW - 1];
    if (lane < 24) {
        float a = s_b[lane];
        #pragma unroll
        for (int j = 0; j < 17; ++j) a = fmaf(s_w[lane * 17 + j], sF[wid][j], a);
        h[(size_t)n * 24 + lane] = a;
    }
}

// ---------------- CSR build ----------------
__global__ void k_count(const int* __restrict__ ei, int* __restrict__ indeg, int E2) {
    int e = blockIdx.x * blockDim.x + threadIdx.x;
    if (e >= E2) return;
    atomicAdd(&indeg[ei[E2 + e]], 1);
}

__global__ void k_scan_bsum(const int* __restrict__ indeg, int* __restrict__ bsum, int N) {
    int base = blockIdx.x * SCB * SCI;
    int t = threadIdx.x;
    int s = 0;
    #pragma unroll
    for (int i = 0; i < SCI; ++i) {
        int idx = base + t * SCI + i;
        if (idx < N) s += indeg[idx];
    }
    #pragma unroll
    for (int o = 32; o >= 1; o >>= 1) s += __shfl_xor(s, o);
    __shared__ int red[SCB / 64];
    if ((t & 63) == 0) red[t >> 6] = s;
    __syncthreads();
    if (t == 0) {
        int tot = 0;
        for (int w = 0; w < SCB / 64; ++w) tot += red[w];
        bsum[blockIdx.x] = tot;
    }
}

__global__ void k_scan_final(const int* __restrict__ indeg, const int* __restrict__ bsum,
                             int* __restrict__ rowptr, int N, int nb) {
    __shared__ int s_t[SCB];
    __shared__ int s_boff;
    int base = blockIdx.x * SCB * SCI;
    int t = threadIdx.x;
    if (t == 0) {
        int off = 0;
        for (int i = 0; i < (int)blockIdx.x; ++i) off += bsum[i];
        s_boff = off;
        if (blockIdx.x == 0) {
            int tot = 0;
            for (int i = 0; i < nb; ++i) tot += bsum[i];
            rowptr[N] = tot;
        }
    }
    int loc[SCI]; int s = 0;
    #pragma unroll
    for (int i = 0; i < SCI; ++i) {
        int idx = base + t * SCI + i;
        int v = (idx < N) ? indeg[idx] : 0;
        loc[i] = s; s += v;
    }
    s_t[t] = s;
    __syncthreads();
    for (int o = 1; o < SCB; o <<= 1) {
        int v = (t >= o) ? s_t[t - o] : 0;
        __syncthreads();
        s_t[t] += v;
        __syncthreads();
    }
    int toff = ((t > 0) ? s_t[t - 1] : 0) + s_boff;
    #pragma unroll
    for (int i = 0; i < SCI; ++i) {
        int idx = base + t * SCI + i;
        if (idx < N) rowptr[idx] = toff + loc[i];
    }
}

__global__ void k_cursor(const int* __restrict__ rowptr, int* __restrict__ cursor, int N) {
    int n = blockIdx.x * blockDim.x + threadIdx.x;
    if (n < N) cursor[n] = rowptr[n];
}

// scatter edges into CSR; duplicate edge attr as packed fp16 in CSR order when dup16
__global__ void k_scatter(const int* __restrict__ ei, int* __restrict__ cursor,
                          int* __restrict__ csr_src, int* __restrict__ csr_aid,
                          unsigned long long* __restrict__ att16, const float* __restrict__ attr,
                          int E2, int EU, int dup16) {
    int e = blockIdx.x * blockDim.x + threadIdx.x;
    if (e >= E2) return;
    int s = ei[e];
    int d = ei[E2 + e];
    int pos = atomicAdd(&cursor[d], 1);
    csr_src[pos] = s;
    int aid = (e < EU) ? e : e - EU;
    if (dup16) {
        float4 av = *(const float4*)(attr + (size_t)aid * 4);
        unsigned lo = f2h_pack(av.x, av.y), hi = f2h_pack(av.z, av.w);
        att16[pos] = (unsigned long long)lo | ((unsigned long long)hi << 32);
    } else {
        csr_aid[pos] = aid;
    }
}

// ---------------- per-node left/right transforms (both fp32) ----------------
template <int IN, int OUT>
__global__ void k_xform(const float* __restrict__ h,
                        const float* __restrict__ wl, const float* __restrict__ bl,
                        const float* __restrict__ wr, const float* __restrict__ br,
                        float* __restrict__ xl, float* __restrict__ xr, int N) {
    __shared__ float s_wl[OUT * IN], s_wr[OUT * IN], s_bl[OUT], s_br[OUT];
    for (int t = threadIdx.x; t < OUT * IN; t += blockDim.x) { s_wl[t] = wl[t]; s_wr[t] = wr[t]; }
    for (int t = threadIdx.x; t < OUT; t += blockDim.x) { s_bl[t] = bl[t]; s_br[t] = br[t]; }
    __syncthreads();
    int n = blockIdx.x * blockDim.x + threadIdx.x;
    if (n >= N) return;
    float f[IN];
    const float* hr = h + (size_t)n * IN;
    #pragma unroll
    for (int j = 0; j < IN; ++j) f[j] = hr[j];
    float* xlr = xl + (size_t)n * OUT;
    float* xrr = xr + (size_t)n * OUT;
    #pragma unroll
    for (int k = 0; k < OUT; ++k) {
        float al = s_bl[k], ar = s_br[k];
        #pragma unroll
        for (int j = 0; j < IN; ++j) {
            al = fmaf(s_wl[k * IN + j], f[j], al);
            ar = fmaf(s_wr[k * IN + j], f[j], ar);
        }
        xlr[k] = al; xrr[k] = ar;
    }
}

// ---------------- fused GATv2: one wave per node, fp32 gathers, fp16 LDS staging ----
// Phase A (lanes = edges): gather xl[src] row float4-wise (fp32 global -> good
// codegen, VGPR=64, r7-verified) -> stage to LDS as packed fp16 words (HALVES the
// LDS footprint -> ~2x occupancy: OUT=36 40.4->21.6KB, OUT=24 27->14.9KB) + logit
// inline from the fp32 values. attr from CSR-ordered fp16 duplicate (coalesced 8B).
// Online softmax via wave reductions; p broadcast via per-wave LDS (all-lane write
// while convergent). Phase B (lanes = channels): quad-accumulator FMA, broadcast
// word + shift unpack (2-lane broadcast reads, conflict-free stride 65).
template <int OUT, int MINW>
__launch_bounds__(256, MINW)
__global__ void k_gat(const int* __restrict__ rowptr, const int* __restrict__ csr_src,
                      const int* __restrict__ csr_aid, const unsigned long long* __restrict__ att16,
                      const float* __restrict__ attr,
                      const float* __restrict__ xl, const float* __restrict__ xr,
                      const float* __restrict__ we, const float* __restrict__ ew,
                      const float* __restrict__ eb, const float* __restrict__ att,
                      const float* __restrict__ bias, float* __restrict__ h, int N) {
    constexpr int Q = OUT / 2;            // packed words per staged row
    __shared__ float sC[OUT * 4], sCb[OUT], sAtt[OUT], sB[OUT];
    __shared__ float sXB[4][OUT];         // xr row + sCb, per wave
    __shared__ unsigned sXL[4][Q * 65];   // staged fp16 words, word-major, stride 65
    __shared__ float sP[4][64];           // per-wave p broadcast (all-lane write)
    // fold edge MLP into GAT edge projection: C = we @ edge_w (OUT x 4), cb = we @ edge_b
    for (int t = threadIdx.x; t < OUT * 5; t += blockDim.x) {
        int k = t / 5, c = t - k * 5;
        float a = 0.f;
        if (c < 4) { for (int j = 0; j < 12; ++j) a += we[k * 12 + j] * ew[j * 4 + c]; sC[k * 4 + c] = a; }
        else       { for (int j = 0; j < 12; ++j) a += we[k * 12 + j] * eb[j];          sCb[k] = a; }
    }
    for (int t = threadIdx.x; t < OUT; t += blockDim.x) { sAtt[t] = att[t]; sB[t] = bias[t]; }
    __syncthreads();

    int wid = threadIdx.x >> 6, lane = threadIdx.x & 63;
    int n = blockIdx.x * 4 + wid;
    if (n >= N) return;   // wave-uniform; no syncthreads after this point

    if (lane < OUT) sXB[wid][lane] = xr[(size_t)n * OUT + lane] + sCb[lane];

    unsigned* myXL = &sXL[wid][0];
    float* myP  = &sP[wid][0];
    int rb = rowptr[n], re = rowptr[n + 1];

    float m = -INFINITY, den = 0.f, acc = 0.f;
    float as0 = 0.f, as1 = 0.f, as2 = 0.f, as3 = 0.f;   // raw-attr sums for self-loop mean

    for (int c0 = rb; c0 < re; c0 += 64) {
        int j = c0 + lane;
        float lg = -INFINITY;
        if (j < re) {
            int s = csr_src[j];
            float ax, ay, az, aw;
            if (att16) {
                unsigned long long au = att16[j];
                unsigned lo = (unsigned)au, hi = (unsigned)(au >> 32);
                ax = h2f_lo(lo); ay = h2f_hi(lo); az = h2f_lo(hi); aw = h2f_hi(hi);
            } else {
                int aid = csr_aid[j];
                float4 av = *(const float4*)(attr + (size_t)aid * 4);
                ax = av.x; ay = av.y; az = av.z; aw = av.w;
            }
            as0 += ax; as1 += ay; as2 += az; as3 += aw;
            const float4* xs4 = (const float4*)(xl + (size_t)s * OUT);
            lg = 0.f;
            #pragma unroll
            for (int q4 = 0; q4 < OUT / 4; ++q4) {
                float4 v = xs4[q4];
                myXL[(2 * q4 + 0) * 65 + lane] = f2h_pack(v.x, v.y);
                myXL[(2 * q4 + 1) * 65 + lane] = f2h_pack(v.z, v.w);
                #pragma unroll
                for (int r = 0; r < 4; ++r) {
                    int k = 4 * q4 + r;
                    float xlv = (r == 0) ? v.x : (r == 1) ? v.y : (r == 2) ? v.z : v.w;
                    float c = sXB[wid][k];
                    c = fmaf(sC[k * 4 + 0], ax, c);
                    c = fmaf(sC[k * 4 + 1], ay, c);
                    c = fmaf(sC[k * 4 + 2], az, c);
                    c = fmaf(sC[k * 4 + 3], aw, c);
                    float mm = xlv + c;
                    float lr = (mm > 0.f) ? mm : 0.2f * mm;
                    lg = fmaf(sAtt[k], lr, lg);
                }
            }
        }
        float cm = wred_max(lg);
        float nm = fmaxf(m, cm);
        float sc = __expf(m - nm);          // m=-inf on first chunk -> 0
        float p = (j < re) ? __expf(lg - nm) : 0.f;
        myP[lane] = p;                      // ALL 64 lanes write (convergent)
        float ps = wred_sum(p);
        den = den * sc + ps;
        m = nm;
        int cnt = min(64, re - c0);
        if (lane < OUT) {
            const int qq = lane >> 1;
            const int sh = (lane & 1) << 4;
            float a0 = 0.f, a1 = 0.f, a2 = 0.f, a3 = 0.f;
            int t = 0;
            for (; t + 3 < cnt; t += 4) {
                a0 = fmaf(myP[t],     h2f_u16((unsigned short)(myXL[qq * 65 + t]     >> sh)), a0);
                a1 = fmaf(myP[t + 1], h2f_u16((unsigned short)(myXL[qq * 65 + t + 1] >> sh)), a1);
                a2 = fmaf(myP[t + 2], h2f_u16((unsigned short)(myXL[qq * 65 + t + 2] >> sh)), a2);
                a3 = fmaf(myP[t + 3], h2f_u16((unsigned short)(myXL[qq * 65 + t + 3] >> sh)), a3);
            }
            for (; t < cnt; ++t)
                a0 = fmaf(myP[t], h2f_u16((unsigned short)(myXL[qq * 65 + t] >> sh)), a0);
            acc = fmaf(acc, sc, (a0 + a1) + (a2 + a3));
        }
    }

    // self-loop: attr = mean of incoming TRANSFORMED attrs (exact-0 if indeg==0)
    as0 = wred_sum(as0); as1 = wred_sum(as1); as2 = wred_sum(as2); as3 = wred_sum(as3);
    int cnt = re - rb;
    float inv = (cnt > 0) ? 1.f / (float)cnt : 0.f;
    float a0 = as0 * inv, a1 = as1 * inv, a2 = as2 * inv, a3 = as3 * inv;

    float xln = 0.f, contrib = 0.f;
    if (lane < OUT) {
        xln = xl[(size_t)n * OUT + lane];
        float dot = 0.f;
        dot = fmaf(sC[lane * 4 + 0], a0, dot);
        dot = fmaf(sC[lane * 4 + 1], a1, dot);
        dot = fmaf(sC[lane * 4 + 2], a2, dot);
        dot = fmaf(sC[lane * 4 + 3], a3, dot);
        // sXB = xr + sCb; when indeg==0 the transformed self attr is 0 -> remove sCb
        float mm = xln + sXB[wid][lane] + ((cnt > 0) ? dot : -sCb[lane]);
        float lr = (mm > 0.f) ? mm : 0.2f * mm;
        contrib = sAtt[lane] * lr;
    }
    float lgs = wred_sum(contrib);
    float nm = fmaxf(m, lgs);
    float sc = __expf(m - nm);
    float p = __expf(lgs - nm);
    den = den * sc + p;                      // den >= p > 0: no div-by-zero
    if (lane < OUT) {
        acc = acc * sc + p * xln;
        float v = acc / den + sB[lane];
        h[(size_t)n * OUT + lane] = (v > 0.f) ? v : 0.f;
    }
}

// ---------------- mean pool: one block per graph, batch is sorted ----------------
__global__ void k_pool(const float* __restrict__ h, const int* __restrict__ batch,
                       float* __restrict__ pmean, int N) {
    int g = blockIdx.x;
    int a = 0, b = N;
    while (a < b) { int mid = (a + b) >> 1; if (batch[mid] < g) a = mid + 1; else b = mid; }
    int lo = a;
    a = lo; b = N;
    while (a < b) { int mid = (a + b) >> 1; if (batch[mid] < g + 1) a = mid + 1; else b = mid; }
    int hi = a;
    int cnt = hi - lo;
    int wid = threadIdx.x >> 6, lane = threadIdx.x & 63;
    float acc = 0.f;
    if (lane < 36) {
        for (int n = lo + wid; n < hi; n += 4) acc += h[(size_t)n * 36 + lane];
    }
    __shared__ float s_acc[4][36];
    if (lane < 36) s_acc[wid][lane] = acc;
    __syncthreads();
    if (threadIdx.x < 36) {
        float v = s_acc[0][threadIdx.x] + s_acc[1][threadIdx.x] +
                  s_acc[2][threadIdx.x] + s_acc[3][threadIdx.x];
        float iv = (cnt > 0) ? 1.f / (float)cnt : 0.f;
        pmean[(size_t)g * 36 + threadIdx.x] = v * iv;
    }
}

// ---------------- final head ----------------
__global__ void k_final(const float* __restrict__ pmean,
                        const float* __restrict__ fw, const float* __restrict__ fb,
                        float* __restrict__ out, int G) {
    int t = blockIdx.x * blockDim.x + threadIdx.x;
    if (t >= G * 64) return;
    int g = t / 64, o = t - g * 64;
    float a = fb[o];
    #pragma unroll
    for (int k = 0; k < 36; ++k) a = fmaf(pmean[(size_t)g * 36 + k], fw[o * 36 + k], a);
    out[t] = a;
}

extern "C" void kernel_launch(void* const* d_in, const int* in_sizes, int n_in,
                              void* d_out, int out_size, void* d_ws, size_t ws_size,
                              hipStream_t stream) {
    const float* x      = (const float*)d_in[0];
    const int*   ei     = (const int*)d_in[1];
    const float* eattr  = (const float*)d_in[2];
    const int*   batch  = (const int*)d_in[3];
    const float* emb    = (const float*)d_in[4];
    const float* node_w = (const float*)d_in[5];
    const float* node_b = (const float*)d_in[6];
    const float* edge_w = (const float*)d_in[7];
    const float* edge_b = (const float*)d_in[8];
    const float* c1_wl  = (const float*)d_in[9];
    const float* c1_bl  = (const float*)d_in[10];
    const float* c1_wr  = (const float*)d_in[11];
    const float* c1_br  = (const float*)d_in[12];
    const float* c1_we  = (const float*)d_in[13];
    const float* c1_att = (const float*)d_in[14];
    const float* c1_bias= (const float*)d_in[15];
    const float* c2_wl  = (const float*)d_in[16];
    const float* c2_bl  = (const float*)d_in[17];
    const float* c2_wr  = (const float*)d_in[18];
    const float* c2_br  = (const float*)d_in[19];
    const float* c2_we  = (const float*)d_in[20];
    const float* c2_att = (const float*)d_in[21];
    const float* c2_bias= (const float*)d_in[22];
    const float* fin_w  = (const float*)d_in[23];
    const float* fin_b  = (const float*)d_in[24];
    float* out = (float*)d_out;

    const int N  = in_sizes[3];
    const int E2 = in_sizes[1] / 2;
    const int EU = in_sizes[2] / 4;
    const int XW = in_sizes[0] / N;
    const int NA = in_sizes[4] / 16;
    const int G  = out_size / 64;

    // workspace layout (4B units); all segments 16B-aligned
    float* ws = (float*)d_ws;
    size_t off = 0;
    float*  h      = ws + off;              off += (size_t)N * 36;
    float*  xl     = ws + off;              off += (size_t)N * 36;
    float*  xr     = ws + off;              off += (size_t)N * 36;
    float*  pmean  = ws + off;              off += (size_t)G * 36;
    int*    rowptr = (int*)(ws + off);      off += (size_t)N + 1;
    int*    cursor = (int*)(ws + off);      off += (size_t)N;
    int*    csr_src= (int*)(ws + off);      off += (size_t)E2;
    int*    csr_aid= (int*)(ws + off);      off += (size_t)E2;
    int*    bsum   = (int*)(ws + off);      off += 64;
    size_t need_base = off * 4;
    off = (off + 1) & ~(size_t)1;           // 8B align
    unsigned long long* att16 = (unsigned long long*)(ws + off);
    off += (size_t)E2 * 2;
    size_t need_full = off * 4;

    if (ws_size < need_base) return;  // loud failure: output stays poisoned
    const int use16 = (ws_size >= need_full) ? 1 : 0;
    unsigned long long* att16_k = use16 ? att16 : (unsigned long long*)nullptr;

    hipMemsetAsync(cursor, 0, (size_t)N * 4, stream);

    dim3 b(TPB);
    dim3 gN((N + TPB - 1) / TPB);
    dim3 gE((E2 + TPB - 1) / TPB);
    dim3 gW((N + 3) / 4);   // 4 waves per block, 1 wave per node
    int nb = (N + SCB * SCI - 1) / (SCB * SCI);

    k_node<<<gW, b, 0, stream>>>(x, emb, node_w, node_b, h, N, XW, NA);
    k_count<<<gE, b, 0, stream>>>(ei, cursor, E2);
    k_scan_bsum<<<nb, SCB, 0, stream>>>(cursor, bsum, N);
    k_scan_final<<<nb, SCB, 0, stream>>>(cursor, bsum, rowptr, N, nb);
    k_cursor<<<gN, b, 0, stream>>>(rowptr, cursor, N);
    k_scatter<<<gE, b, 0, stream>>>(ei, cursor, csr_src, csr_aid, att16, eattr, E2, EU, use16);

    // ---- layer 1 (24 -> 24): ~14.9KB LDS -> 8 blocks/CU (wave cap, 100% occ) ----
    k_xform<24, 24><<<gN, b, 0, stream>>>(h, c1_wl, c1_bl, c1_wr, c1_br, xl, xr, N);
    k_gat<24, 6><<<gW, b, 0, stream>>>(rowptr, csr_src, csr_aid, att16_k, eattr, xl, xr,
                                       c1_we, edge_w, edge_b, c1_att, c1_bias, h, N);

    // ---- layer 2 (24 -> 36): ~21.6KB LDS -> 7 blocks/CU (~87% occ) ----
    k_xform<24, 36><<<gN, b, 0, stream>>>(h, c2_wl, c2_bl, c2_wr, c2_br, xl, xr, N);
    k_gat<36, 4><<<gW, b, 0, stream>>>(rowptr, csr_src, csr_aid, att16_k, eattr, xl, xr,
                                       c2_we, edge_w, edge_b, c2_att, c2_bias, h, N);

    // ---- pool + head ----
    k_pool<<<G, b, 0, stream>>>(h, batch, pmean, N);
    k_final<<<(G * 64 + TPB - 1) / TPB, b, 0, stream>>>(pmean, fin_w, fin_b, out, G);
}

// Round 11
// 733.264 us; speedup vs baseline: 9.5671x; 3.3898x over previous
//
#include <hip/hip_runtime.h>
#include <hip/hip_fp16.h>

#define TPB 256
#define SCB 256
#define SCI 16   // scan items per thread -> 4096 per block

typedef unsigned u32x4 __attribute__((ext_vector_type(4)));

__device__ __forceinline__ float wred_max(float v) {
    #pragma unroll
    for (int o = 32; o >= 1; o >>= 1) v = fmaxf(v, __shfl_xor(v, o));
    return v;
}
__device__ __forceinline__ float wred_sum(float v) {
    #pragma unroll
    for (int o = 32; o >= 1; o >>= 1) v += __shfl_xor(v, o);
    return v;
}
__device__ __forceinline__ float h2f_u16(unsigned short u) {
    __half_raw r; r.x = u; return __half2float(__half(r));
}
__device__ __forceinline__ float h2f_lo(unsigned u) { return h2f_u16((unsigned short)(u & 0xffffu)); }
__device__ __forceinline__ float h2f_hi(unsigned u) { return h2f_u16((unsigned short)(u >> 16)); }
__device__ __forceinline__ unsigned f2h_pack(float a, float b) {
    __half ha = __float2half(a), hb = __float2half(b);
    __half_raw ra = *(__half_raw*)&ha, rb = *(__half_raw*)&hb;
    return (unsigned)ra.x | ((unsigned)rb.x << 16);
}

// ---------------- node featurizer: wave per node (coalesced x reads) ----------------
__global__ void k_node(const float* __restrict__ x, const float* __restrict__ emb,
                       const float* __restrict__ nw, const float* __restrict__ nbv,
                       float* __restrict__ h, int N, int XW, int NA) {
    __shared__ float s_w[24 * 17];
    __shared__ float s_b[24];
    __shared__ float sF[4][20];
    for (int t = threadIdx.x; t < 24 * 17; t += blockDim.x) s_w[t] = nw[t];
    for (int t = threadIdx.x; t < 24; t += blockDim.x) s_b[t] = nbv[t];
    __syncthreads();
    int wid = threadIdx.x >> 6, lane = threadIdx.x & 63;
    int n = blockIdx.x * 4 + wid;
    if (n >= N) return;
    const float* row = x + (size_t)n * XW;
    float v0 = (lane < NA) ? row[lane] : -3.4e38f;
    float v1 = (lane + 64 < NA) ? row[lane + 64] : -3.4e38f;
    float bv; int bi;
    if (v1 > v0) { bv = v1; bi = lane + 64; } else { bv = v0; bi = lane; }
    #pragma unroll
    for (int o = 32; o >= 1; o >>= 1) {
        float ov = __shfl_xor(bv, o); int oi = __shfl_xor(bi, o);
        if (ov > bv || (ov == bv && oi < bi)) { bv = ov; bi = oi; }
    }
    if (lane < 16) sF[wid][lane] = emb[(size_t)bi * 16 + lane];
    if (lane == 16) sF[wid][16] = row[XW - 1];
    if (lane < 24) {
        float a = s_b[lane];
        #pragma unroll
        for (int j = 0; j < 17; ++j) a = fmaf(s_w[lane * 17 + j], sF[wid][j], a);
        h[(size_t)n * 24 + lane] = a;
    }
}

// ---------------- CSR build ----------------
__global__ void k_count(const int* __restrict__ ei, int* __restrict__ indeg, int E2) {
    int e = blockIdx.x * blockDim.x + threadIdx.x;
    if (e >= E2) return;
    atomicAdd(&indeg[ei[E2 + e]], 1);
}

__global__ void k_scan_bsum(const int* __restrict__ indeg, int* __restrict__ bsum, int N) {
    int base = blockIdx.x * SCB * SCI;
    int t = threadIdx.x;
    int s = 0;
    #pragma unroll
    for (int i = 0; i < SCI; ++i) {
        int idx = base + t * SCI + i;
        if (idx < N) s += indeg[idx];
    }
    #pragma unroll
    for (int o = 32; o >= 1; o >>= 1) s += __shfl_xor(s, o);
    __shared__ int red[SCB / 64];
    if ((t & 63) == 0) red[t >> 6] = s;
    __syncthreads();
    if (t == 0) {
        int tot = 0;
        for (int w = 0; w < SCB / 64; ++w) tot += red[w];
        bsum[blockIdx.x] = tot;
    }
}

__global__ void k_scan_final(const int* __restrict__ indeg, const int* __restrict__ bsum,
                             int* __restrict__ rowptr, int N, int nb) {
    __shared__ int s_t[SCB];
    __shared__ int s_boff;
    int base = blockIdx.x * SCB * SCI;
    int t = threadIdx.x;
    if (t == 0) {
        int off = 0;
        for (int i = 0; i < (int)blockIdx.x; ++i) off += bsum[i];
        s_boff = off;
        if (blockIdx.x == 0) {
            int tot = 0;
            for (int i = 0; i < nb; ++i) tot += bsum[i];
            rowptr[N] = tot;
        }
    }
    int loc[SCI]; int s = 0;
    #pragma unroll
    for (int i = 0; i < SCI; ++i) {
        int idx = base + t * SCI + i;
        int v = (idx < N) ? indeg[idx] : 0;
        loc[i] = s; s += v;
    }
    s_t[t] = s;
    __syncthreads();
    for (int o = 1; o < SCB; o <<= 1) {
        int v = (t >= o) ? s_t[t - o] : 0;
        __syncthreads();
        s_t[t] += v;
        __syncthreads();
    }
    int toff = ((t > 0) ? s_t[t - 1] : 0) + s_boff;
    #pragma unroll
    for (int i = 0; i < SCI; ++i) {
        int idx = base + t * SCI + i;
        if (idx < N) rowptr[idx] = toff + loc[i];
    }
}

__global__ void k_cursor(const int* __restrict__ rowptr, int* __restrict__ cursor, int N) {
    int n = blockIdx.x * blockDim.x + threadIdx.x;
    if (n < N) cursor[n] = rowptr[n];
}

// scatter edges into CSR; duplicate edge attr as packed fp16 in CSR order when dup16
__global__ void k_scatter(const int* __restrict__ ei, int* __restrict__ cursor,
                          int* __restrict__ csr_src, int* __restrict__ csr_aid,
                          unsigned long long* __restrict__ att16, const float* __restrict__ attr,
                          int E2, int EU, int dup16) {
    int e = blockIdx.x * blockDim.x + threadIdx.x;
    if (e >= E2) return;
    int s = ei[e];
    int d = ei[E2 + e];
    int pos = atomicAdd(&cursor[d], 1);
    csr_src[pos] = s;
    int aid = (e < EU) ? e : e - EU;
    if (dup16) {
        float4 av = *(const float4*)(attr + (size_t)aid * 4);
        unsigned lo = f2h_pack(av.x, av.y), hi = f2h_pack(av.z, av.w);
        att16[pos] = (unsigned long long)lo | ((unsigned long long)hi << 32);
    } else {
        csr_aid[pos] = aid;
    }
}

// ---------------- per-node transforms: xl -> packed fp16 words, xr -> fp32 ----------------
template <int IN, int OUT, int GXSW>   // GXSW = u32 words per xl row (16B-aligned stride)
__global__ void k_xform(const float* __restrict__ h,
                        const float* __restrict__ wl, const float* __restrict__ bl,
                        const float* __restrict__ wr, const float* __restrict__ br,
                        unsigned* __restrict__ xl, float* __restrict__ xr, int N) {
    __shared__ float s_wl[OUT * IN], s_wr[OUT * IN], s_bl[OUT], s_br[OUT];
    for (int t = threadIdx.x; t < OUT * IN; t += blockDim.x) { s_wl[t] = wl[t]; s_wr[t] = wr[t]; }
    for (int t = threadIdx.x; t < OUT; t += blockDim.x) { s_bl[t] = bl[t]; s_br[t] = br[t]; }
    __syncthreads();
    int n = blockIdx.x * blockDim.x + threadIdx.x;
    if (n >= N) return;
    float f[IN];
    const float* hr = h + (size_t)n * IN;
    #pragma unroll
    for (int j = 0; j < IN; ++j) f[j] = hr[j];
    unsigned* xo = xl + (size_t)n * GXSW;
    #pragma unroll
    for (int q = 0; q < OUT / 2; ++q) {
        float a0 = s_bl[2 * q], a1 = s_bl[2 * q + 1];
        #pragma unroll
        for (int j = 0; j < IN; ++j) {
            a0 = fmaf(s_wl[(2 * q) * IN + j], f[j], a0);
            a1 = fmaf(s_wl[(2 * q + 1) * IN + j], f[j], a1);
        }
        xo[q] = f2h_pack(a0, a1);
    }
    float* xrr = xr + (size_t)n * OUT;
    #pragma unroll
    for (int k = 0; k < OUT; ++k) {
        float ar = s_br[k];
        #pragma unroll
        for (int j = 0; j < IN; ++j) ar = fmaf(s_wr[k * IN + j], f[j], ar);
        xrr[k] = ar;
    }
}

// ---------------- fused GATv2: one wave per node, fp16 rows via forced-wide loads ----
// Phase A (lanes = edges): gather packed-fp16 xl[src] row with a single inline-asm
// block of 3/5 global_load_dwordx4 + s_waitcnt vmcnt(0) (forces wide loads -- r6/r8
// showed the compiler scalarizes fp16 row loads otherwise; self-contained vmcnt keeps
// the compiler's own waitcnt accounting conservative-safe). Requests/row: 9->5 (OUT=36),
// 6->3 (OUT=24); empirically FETCH ~ edges x requests x 64B. Stage words to LDS
// (word-major, stride 65) + logit inline. attr from CSR-ordered fp16 stream. Online
// softmax via wave reductions; p broadcast via per-wave LDS (all-lane write while
// convergent). Phase B (lanes = channels): quad-accumulator FMA, broadcast word +
// shift unpack.
template <int OUT, int GXSW, int MINW>
__launch_bounds__(256, MINW)
__global__ void k_gat(const int* __restrict__ rowptr, const int* __restrict__ csr_src,
                      const int* __restrict__ csr_aid, const unsigned long long* __restrict__ att16,
                      const float* __restrict__ attr,
                      const unsigned* __restrict__ xl32, const float* __restrict__ xr,
                      const float* __restrict__ we, const float* __restrict__ ew,
                      const float* __restrict__ eb, const float* __restrict__ att,
                      const float* __restrict__ bias, float* __restrict__ h, int N) {
    constexpr int Q = OUT / 2;            // packed words per row
    constexpr int NW4 = GXSW / 4;         // dwordx4 loads per row (3 for 24, 5 for 36)
    __shared__ float sC[OUT * 4], sCb[OUT], sAtt[OUT], sB[OUT];
    __shared__ float sXB[4][OUT];         // xr row + sCb, per wave
    __shared__ unsigned sXL[4][Q * 65];   // staged fp16 words, word-major, stride 65
    __shared__ float sP[4][64];           // per-wave p broadcast (all-lane write)
    // fold edge MLP into GAT edge projection: C = we @ edge_w (OUT x 4), cb = we @ edge_b
    for (int t = threadIdx.x; t < OUT * 5; t += blockDim.x) {
        int k = t / 5, c = t - k * 5;
        float a = 0.f;
        if (c < 4) { for (int j = 0; j < 12; ++j) a += we[k * 12 + j] * ew[j * 4 + c]; sC[k * 4 + c] = a; }
        else       { for (int j = 0; j < 12; ++j) a += we[k * 12 + j] * eb[j];          sCb[k] = a; }
    }
    for (int t = threadIdx.x; t < OUT; t += blockDim.x) { sAtt[t] = att[t]; sB[t] = bias[t]; }
    __syncthreads();

    int wid = threadIdx.x >> 6, lane = threadIdx.x & 63;
    int n = blockIdx.x * 4 + wid;
    if (n >= N) return;   // wave-uniform; no syncthreads after this point

    if (lane < OUT) sXB[wid][lane] = xr[(size_t)n * OUT + lane] + sCb[lane];

    unsigned* myXL = &sXL[wid][0];
    float* myP  = &sP[wid][0];
    int rb = rowptr[n], re = rowptr[n + 1];

    float m = -INFINITY, den = 0.f, acc = 0.f;
    float as0 = 0.f, as1 = 0.f, as2 = 0.f, as3 = 0.f;   // raw-attr sums for self-loop mean

    for (int c0 = rb; c0 < re; c0 += 64) {
        int j = c0 + lane;
        float lg = -INFINITY;
        if (j < re) {
            int s = csr_src[j];
            float ax, ay, az, aw;
            if (att16) {
                unsigned long long au = att16[j];
                unsigned lo = (unsigned)au, hi = (unsigned)(au >> 32);
                ax = h2f_lo(lo); ay = h2f_hi(lo); az = h2f_lo(hi); aw = h2f_hi(hi);
            } else {
                int aid = csr_aid[j];
                float4 av = *(const float4*)(attr + (size_t)aid * 4);
                ax = av.x; ay = av.y; az = av.z; aw = av.w;
            }
            as0 += ax; as1 += ay; as2 += az; as3 += aw;

            const unsigned* rowp = xl32 + (size_t)s * GXSW;
            u32x4 w0, w1, w2, w3, w4;
            if constexpr (NW4 == 3) {
                asm volatile(
                    "global_load_dwordx4 %0, %3, off\n\t"
                    "global_load_dwordx4 %1, %3, off offset:16\n\t"
                    "global_load_dwordx4 %2, %3, off offset:32\n\t"
                    "s_waitcnt vmcnt(0)"
                    : "=&v"(w0), "=&v"(w1), "=&v"(w2)
                    : "v"(rowp));
            } else {
                asm volatile(
                    "global_load_dwordx4 %0, %5, off\n\t"
                    "global_load_dwordx4 %1, %5, off offset:16\n\t"
                    "global_load_dwordx4 %2, %5, off offset:32\n\t"
                    "global_load_dwordx4 %3, %5, off offset:48\n\t"
                    "global_load_dwordx4 %4, %5, off offset:64\n\t"
                    "s_waitcnt vmcnt(0)"
                    : "=&v"(w0), "=&v"(w1), "=&v"(w2), "=&v"(w3), "=&v"(w4)
                    : "v"(rowp));
            }
            lg = 0.f;
            #pragma unroll
            for (int q = 0; q < Q; ++q) {
                unsigned u = (q < 4) ? w0[q & 3] : (q < 8) ? w1[q & 3] :
                             (q < 12) ? w2[q & 3] : (q < 16) ? w3[q & 3] : w4[q & 3];
                myXL[q * 65 + lane] = u;
                float f0 = h2f_lo(u), f1 = h2f_hi(u);
                int k0 = 2 * q, k1 = 2 * q + 1;
                float c0v = sXB[wid][k0];
                c0v = fmaf(sC[k0 * 4 + 0], ax, c0v);
                c0v = fmaf(sC[k0 * 4 + 1], ay, c0v);
                c0v = fmaf(sC[k0 * 4 + 2], az, c0v);
                c0v = fmaf(sC[k0 * 4 + 3], aw, c0v);
                float m0 = f0 + c0v;
                float lr0 = (m0 > 0.f) ? m0 : 0.2f * m0;
                lg = fmaf(sAtt[k0], lr0, lg);
                float c1v = sXB[wid][k1];
                c1v = fmaf(sC[k1 * 4 + 0], ax, c1v);
                c1v = fmaf(sC[k1 * 4 + 1], ay, c1v);
                c1v = fmaf(sC[k1 * 4 + 2], az, c1v);
                c1v = fmaf(sC[k1 * 4 + 3], aw, c1v);
                float m1 = f1 + c1v;
                float lr1 = (m1 > 0.f) ? m1 : 0.2f * m1;
                lg = fmaf(sAtt[k1], lr1, lg);
            }
        }
        float cm = wred_max(lg);
        float nm = fmaxf(m, cm);
        float sc = __expf(m - nm);          // m=-inf on first chunk -> 0
        float p = (j < re) ? __expf(lg - nm) : 0.f;
        myP[lane] = p;                      // ALL 64 lanes write (convergent)
        float ps = wred_sum(p);
        den = den * sc + ps;
        m = nm;
        int cnt = min(64, re - c0);
        if (lane < OUT) {
            const int qq = lane >> 1;
            const int sh = (lane & 1) << 4;
            float a0 = 0.f, a1 = 0.f, a2 = 0.f, a3 = 0.f;
            int t = 0;
            for (; t + 3 < cnt; t += 4) {
                a0 = fmaf(myP[t],     h2f_u16((unsigned short)(myXL[qq * 65 + t]     >> sh)), a0);
                a1 = fmaf(myP[t + 1], h2f_u16((unsigned short)(myXL[qq * 65 + t + 1] >> sh)), a1);
                a2 = fmaf(myP[t + 2], h2f_u16((unsigned short)(myXL[qq * 65 + t + 2] >> sh)), a2);
                a3 = fmaf(myP[t + 3], h2f_u16((unsigned short)(myXL[qq * 65 + t + 3] >> sh)), a3);
            }
            for (; t < cnt; ++t)
                a0 = fmaf(myP[t], h2f_u16((unsigned short)(myXL[qq * 65 + t] >> sh)), a0);
            acc = fmaf(acc, sc, (a0 + a1) + (a2 + a3));
        }
    }

    // self-loop: attr = mean of incoming TRANSFORMED attrs (exact-0 if indeg==0)
    as0 = wred_sum(as0); as1 = wred_sum(as1); as2 = wred_sum(as2); as3 = wred_sum(as3);
    int cnt = re - rb;
    float inv = (cnt > 0) ? 1.f / (float)cnt : 0.f;
    float a0 = as0 * inv, a1 = as1 * inv, a2 = as2 * inv, a3 = as3 * inv;

    float xln = 0.f, contrib = 0.f;
    if (lane < OUT) {
        unsigned u = xl32[(size_t)n * GXSW + (lane >> 1)];
        xln = h2f_u16((unsigned short)(u >> ((lane & 1) << 4)));
        float dot = 0.f;
        dot = fmaf(sC[lane * 4 + 0], a0, dot);
        dot = fmaf(sC[lane * 4 + 1], a1, dot);
        dot = fmaf(sC[lane * 4 + 2], a2, dot);
        dot = fmaf(sC[lane * 4 + 3], a3, dot);
        // sXB = xr + sCb; when indeg==0 the transformed self attr is 0 -> remove sCb
        float mm = xln + sXB[wid][lane] + ((cnt > 0) ? dot : -sCb[lane]);
        float lr = (mm > 0.f) ? mm : 0.2f * mm;
        contrib = sAtt[lane] * lr;
    }
    float lgs = wred_sum(contrib);
    float nm = fmaxf(m, lgs);
    float sc = __expf(m - nm);
    float p = __expf(lgs - nm);
    den = den * sc + p;                      // den >= p > 0: no div-by-zero
    if (lane < OUT) {
        acc = acc * sc + p * xln;
        float v = acc / den + sB[lane];
        h[(size_t)n * OUT + lane] = (v > 0.f) ? v : 0.f;
    }
}

// ---------------- mean pool: one block per graph, batch is sorted ----------------
__global__ void k_pool(const float* __restrict__ h, const int* __restrict__ batch,
                       float* __restrict__ pmean, int N) {
    int g = blockIdx.x;
    int a = 0, b = N;
    while (a < b) { int mid = (a + b) >> 1; if (batch[mid] < g) a = mid + 1; else b = mid; }
    int lo = a;
    a = lo; b = N;
    while (a < b) { int mid = (a + b) >> 1; if (batch[mid] < g + 1) a = mid + 1; else b = mid; }
    int hi = a;
    int cnt = hi - lo;
    int wid = threadIdx.x >> 6, lane = threadIdx.x & 63;
    float acc = 0.f;
    if (lane < 36) {
        for (int n = lo + wid; n < hi; n += 4) acc += h[(size_t)n * 36 + lane];
    }
    __shared__ float s_acc[4][36];
    if (lane < 36) s_acc[wid][lane] = acc;
    __syncthreads();
    if (threadIdx.x < 36) {
        float v = s_acc[0][threadIdx.x] + s_acc[1][threadIdx.x] +
                  s_acc[2][threadIdx.x] + s_acc[3][threadIdx.x];
        float iv = (cnt > 0) ? 1.f / (float)cnt : 0.f;
        pmean[(size_t)g * 36 + threadIdx.x] = v * iv;
    }
}

// ---------------- final head ----------------
__global__ void k_final(const float* __restrict__ pmean,
                        const float* __restrict__ fw, const float* __restrict__ fb,
                        float* __restrict__ out, int G) {
    int t = blockIdx.x * blockDim.x + threadIdx.x;
    if (t >= G * 64) return;
    int g = t / 64, o = t - g * 64;
    float a = fb[o];
    #pragma unroll
    for (int k = 0; k < 36; ++k) a = fmaf(pmean[(size_t)g * 36 + k], fw[o * 36 + k], a);
    out[t] = a;
}

extern "C" void kernel_launch(void* const* d_in, const int* in_sizes, int n_in,
                              void* d_out, int out_size, void* d_ws, size_t ws_size,
                              hipStream_t stream) {
    const float* x      = (const float*)d_in[0];
    const int*   ei     = (const int*)d_in[1];
    const float* eattr  = (const float*)d_in[2];
    const int*   batch  = (const int*)d_in[3];
    const float* emb    = (const float*)d_in[4];
    const float* node_w = (const float*)d_in[5];
    const float* node_b = (const float*)d_in[6];
    const float* edge_w = (const float*)d_in[7];
    const float* edge_b = (const float*)d_in[8];
    const float* c1_wl  = (const float*)d_in[9];
    const float* c1_bl  = (const float*)d_in[10];
    const float* c1_wr  = (const float*)d_in[11];
    const float* c1_br  = (const float*)d_in[12];
    const float* c1_we  = (const float*)d_in[13];
    const float* c1_att = (const float*)d_in[14];
    const float* c1_bias= (const float*)d_in[15];
    const float* c2_wl  = (const float*)d_in[16];
    const float* c2_bl  = (const float*)d_in[17];
    const float* c2_wr  = (const float*)d_in[18];
    const float* c2_br  = (const float*)d_in[19];
    const float* c2_we  = (const float*)d_in[20];
    const float* c2_att = (const float*)d_in[21];
    const float* c2_bias= (const float*)d_in[22];
    const float* fin_w  = (const float*)d_in[23];
    const float* fin_b  = (const float*)d_in[24];
    float* out = (float*)d_out;

    const int N  = in_sizes[3];
    const int E2 = in_sizes[1] / 2;
    const int EU = in_sizes[2] / 4;
    const int XW = in_sizes[0] / N;
    const int NA = in_sizes[4] / 16;
    const int G  = out_size / 64;

    // workspace layout (4B units); all segments 16B-aligned
    float* ws = (float*)d_ws;
    size_t off = 0;
    float*    h      = ws + off;              off += (size_t)N * 36;
    unsigned* xl32   = (unsigned*)(ws + off); off += (size_t)N * 20;   // 20-word (80B) max row stride
    float*    xr     = ws + off;              off += (size_t)N * 36;
    float*    pmean  = ws + off;              off += (size_t)G * 36;
    int*      rowptr = (int*)(ws + off);      off += (size_t)N + 1;
    int*      cursor = (int*)(ws + off);      off += (size_t)N;
    int*      csr_src= (int*)(ws + off);      off += (size_t)E2;
    int*      csr_aid= (int*)(ws + off);      off += (size_t)E2;
    int*      bsum   = (int*)(ws + off);      off += 64;
    size_t need_base = off * 4;
    off = (off + 1) & ~(size_t)1;             // 8B align
    unsigned long long* att16 = (unsigned long long*)(ws + off);
    off += (size_t)E2 * 2;
    size_t need_full = off * 4;

    if (ws_size < need_base) return;  // loud failure: output stays poisoned
    const int use16 = (ws_size >= need_full) ? 1 : 0;
    unsigned long long* att16_k = use16 ? att16 : (unsigned long long*)nullptr;

    hipMemsetAsync(cursor, 0, (size_t)N * 4, stream);

    dim3 b(TPB);
    dim3 gN((N + TPB - 1) / TPB);
    dim3 gE((E2 + TPB - 1) / TPB);
    dim3 gW((N + 3) / 4);   // 4 waves per block, 1 wave per node
    int nb = (N + SCB * SCI - 1) / (SCB * SCI);

    k_node<<<gW, b, 0, stream>>>(x, emb, node_w, node_b, h, N, XW, NA);
    k_count<<<gE, b, 0, stream>>>(ei, cursor, E2);
    k_scan_bsum<<<nb, SCB, 0, stream>>>(cursor, bsum, N);
    k_scan_final<<<nb, SCB, 0, stream>>>(cursor, bsum, rowptr, N, nb);
    k_cursor<<<gN, b, 0, stream>>>(rowptr, cursor, N);
    k_scatter<<<gE, b, 0, stream>>>(ei, cursor, csr_src, csr_aid, att16, eattr, E2, EU, use16);

    // ---- layer 1 (24 -> 24): GXSW=12 (48B rows, 3 dwordx4), ~14.9KB LDS ----
    k_xform<24, 24, 12><<<gN, b, 0, stream>>>(h, c1_wl, c1_bl, c1_wr, c1_br, xl32, xr, N);
    k_gat<24, 12, 6><<<gW, b, 0, stream>>>(rowptr, csr_src, csr_aid, att16_k, eattr, xl32, xr,
                                           c1_we, edge_w, edge_b, c1_att, c1_bias, h, N);

    // ---- layer 2 (24 -> 36): GXSW=20 (80B rows, 5 dwordx4), ~21.6KB LDS ----
    k_xform<24, 36, 20><<<gN, b, 0, stream>>>(h, c2_wl, c2_bl, c2_wr, c2_br, xl32, xr, N);
    k_gat<36, 20, 4><<<gW, b, 0, stream>>>(rowptr, csr_src, csr_aid, att16_k, eattr, xl32, xr,
                                           c2_we, edge_w, edge_b, c2_att, c2_bias, h, N);

    // ---- pool + head ----
    k_pool<<<G, b, 0, stream>>>(h, batch, pmean, N);
    k_final<<<(G * 64 + TPB - 1) / TPB, b, 0, stream>>>(pmean, fin_w, fin_b, out, G);
}

// Round 12
// 563.056 us; speedup vs baseline: 12.4592x; 1.3023x over previous
//
#include <hip/hip_runtime.h>
#include <hip/hip_fp16.h>

#define TPB 256
#define SCB 256
#define SCI 16   // scan items per thread -> 4096 per block

typedef unsigned u32x4 __attribute__((ext_vector_type(4)));

__device__ __forceinline__ float wred_max(float v) {
    #pragma unroll
    for (int o = 32; o >= 1; o >>= 1) v = fmaxf(v, __shfl_xor(v, o));
    return v;
}
__device__ __forceinline__ float wred_sum(float v) {
    #pragma unroll
    for (int o = 32; o >= 1; o >>= 1) v += __shfl_xor(v, o);
    return v;
}
__device__ __forceinline__ float h2f_u16(unsigned short u) {
    __half_raw r; r.x = u; return __half2float(__half(r));
}
__device__ __forceinline__ float h2f_lo(unsigned u) { return h2f_u16((unsigned short)(u & 0xffffu)); }
__device__ __forceinline__ float h2f_hi(unsigned u) { return h2f_u16((unsigned short)(u >> 16)); }
__device__ __forceinline__ unsigned f2h_pack(float a, float b) {
    __half ha = __float2half(a), hb = __float2half(b);
    __half_raw ra = *(__half_raw*)&ha, rb = *(__half_raw*)&hb;
    return (unsigned)ra.x | ((unsigned)rb.x << 16);
}

// ---------------- node featurizer: wave per node (coalesced x reads) ----------------
__global__ void k_node(const float* __restrict__ x, const float* __restrict__ emb,
                       const float* __restrict__ nw, const float* __restrict__ nbv,
                       float* __restrict__ h, int N, int XW, int NA) {
    __shared__ float s_w[24 * 17];
    __shared__ float s_b[24];
    __shared__ float sF[4][20];
    for (int t = threadIdx.x; t < 24 * 17; t += blockDim.x) s_w[t] = nw[t];
    for (int t = threadIdx.x; t < 24; t += blockDim.x) s_b[t] = nbv[t];
    __syncthreads();
    int wid = threadIdx.x >> 6, lane = threadIdx.x & 63;
    int n = blockIdx.x * 4 + wid;
    if (n >= N) return;
    const float* row = x + (size_t)n * XW;
    float v0 = (lane < NA) ? row[lane] : -3.4e38f;
    float v1 = (lane + 64 < NA) ? row[lane + 64] : -3.4e38f;
    float bv; int bi;
    if (v1 > v0) { bv = v1; bi = lane + 64; } else { bv = v0; bi = lane; }
    #pragma unroll
    for (int o = 32; o >= 1; o >>= 1) {
        float ov = __shfl_xor(bv, o); int oi = __shfl_xor(bi, o);
        if (ov > bv || (ov == bv && oi < bi)) { bv = ov; bi = oi; }
    }
    if (lane < 16) sF[wid][lane] = emb[(size_t)bi * 16 + lane];
    if (lane == 16) sF[wid][16] = row[XW - 1];
    if (lane < 24) {
        float a = s_b[lane];
        #pragma unroll
        for (int j = 0; j < 17; ++j) a = fmaf(s_w[lane * 17 + j], sF[wid][j], a);
        h[(size_t)n * 24 + lane] = a;
    }
}

// ---------------- CSR build: count + per-edge rank (atomic returns rank) ----------------
__global__ void k_count(const int* __restrict__ ei, int* __restrict__ indeg,
                        int* __restrict__ rank, int E2) {
    int e = blockIdx.x * blockDim.x + threadIdx.x;
    if (e >= E2) return;
    rank[e] = atomicAdd(&indeg[ei[E2 + e]], 1);
}

__global__ void k_scan_bsum(const int* __restrict__ indeg, int* __restrict__ bsum, int N) {
    int base = blockIdx.x * SCB * SCI;
    int t = threadIdx.x;
    int s = 0;
    #pragma unroll
    for (int i = 0; i < SCI; ++i) {
        int idx = base + t * SCI + i;
        if (idx < N) s += indeg[idx];
    }
    #pragma unroll
    for (int o = 32; o >= 1; o >>= 1) s += __shfl_xor(s, o);
    __shared__ int red[SCB / 64];
    if ((t & 63) == 0) red[t >> 6] = s;
    __syncthreads();
    if (t == 0) {
        int tot = 0;
        for (int w = 0; w < SCB / 64; ++w) tot += red[w];
        bsum[blockIdx.x] = tot;
    }
}

__global__ void k_scan_final(const int* __restrict__ indeg, const int* __restrict__ bsum,
                             int* __restrict__ rowptr, int N, int nb) {
    __shared__ int s_t[SCB];
    __shared__ int s_boff;
    int base = blockIdx.x * SCB * SCI;
    int t = threadIdx.x;
    if (t == 0) {
        int off = 0;
        for (int i = 0; i < (int)blockIdx.x; ++i) off += bsum[i];
        s_boff = off;
        if (blockIdx.x == 0) {
            int tot = 0;
            for (int i = 0; i < nb; ++i) tot += bsum[i];
            rowptr[N] = tot;
        }
    }
    int loc[SCI]; int s = 0;
    #pragma unroll
    for (int i = 0; i < SCI; ++i) {
        int idx = base + t * SCI + i;
        int v = (idx < N) ? indeg[idx] : 0;
        loc[i] = s; s += v;
    }
    s_t[t] = s;
    __syncthreads();
    for (int o = 1; o < SCB; o <<= 1) {
        int v = (t >= o) ? s_t[t - o] : 0;
        __syncthreads();
        s_t[t] += v;
        __syncthreads();
    }
    int toff = ((t > 0) ? s_t[t - 1] : 0) + s_boff;
    #pragma unroll
    for (int i = 0; i < SCI; ++i) {
        int idx = base + t * SCI + i;
        if (idx < N) rowptr[idx] = toff + loc[i];
    }
}

// scatter edges into CSR as fused 16B records {src, att_lo, att_hi, 0}; NO atomics
// (pos = rowptr[dst] + rank[e]; rank from k_count's returned old-count)
__global__ void k_scatter(const int* __restrict__ ei, const int* __restrict__ rowptr,
                          const int* __restrict__ rank, const float* __restrict__ attr,
                          uint4* __restrict__ rec, int E2, int EU) {
    int e = blockIdx.x * blockDim.x + threadIdx.x;
    if (e >= E2) return;
    int s = ei[e];
    int d = ei[E2 + e];
    int pos = rowptr[d] + rank[e];
    int aid = (e < EU) ? e : e - EU;
    float4 av = *(const float4*)(attr + (size_t)aid * 4);
    rec[pos] = make_uint4((unsigned)s, f2h_pack(av.x, av.y), f2h_pack(av.z, av.w), 0u);
}

// ---------------- per-node transforms: xl -> packed fp16 words, xr -> fp32 ----------------
template <int IN, int OUT, int GXSW>   // GXSW = u32 words per xl row (16B-aligned stride)
__global__ void k_xform(const float* __restrict__ h,
                        const float* __restrict__ wl, const float* __restrict__ bl,
                        const float* __restrict__ wr, const float* __restrict__ br,
                        unsigned* __restrict__ xl, float* __restrict__ xr, int N) {
    __shared__ float s_wl[OUT * IN], s_wr[OUT * IN], s_bl[OUT], s_br[OUT];
    for (int t = threadIdx.x; t < OUT * IN; t += blockDim.x) { s_wl[t] = wl[t]; s_wr[t] = wr[t]; }
    for (int t = threadIdx.x; t < OUT; t += blockDim.x) { s_bl[t] = bl[t]; s_br[t] = br[t]; }
    __syncthreads();
    int n = blockIdx.x * blockDim.x + threadIdx.x;
    if (n >= N) return;
    float f[IN];
    const float* hr = h + (size_t)n * IN;
    #pragma unroll
    for (int j = 0; j < IN; ++j) f[j] = hr[j];
    unsigned* xo = xl + (size_t)n * GXSW;
    #pragma unroll
    for (int q = 0; q < OUT / 2; ++q) {
        float a0 = s_bl[2 * q], a1 = s_bl[2 * q + 1];
        #pragma unroll
        for (int j = 0; j < IN; ++j) {
            a0 = fmaf(s_wl[(2 * q) * IN + j], f[j], a0);
            a1 = fmaf(s_wl[(2 * q + 1) * IN + j], f[j], a1);
        }
        xo[q] = f2h_pack(a0, a1);
    }
    float* xrr = xr + (size_t)n * OUT;
    #pragma unroll
    for (int k = 0; k < OUT; ++k) {
        float ar = s_br[k];
        #pragma unroll
        for (int j = 0; j < IN; ++j) ar = fmaf(s_wr[k * IN + j], f[j], ar);
        xrr[k] = ar;
    }
}

// ---------------- fused GATv2: one wave per node, fp16 rows via forced-wide loads ----
// Phase A (lanes = edges): one coalesced dwordx4 edge-record load {src, attr fp16x4},
// then gather packed-fp16 xl[src] row with a single inline-asm block of 3/5
// global_load_dwordx4 + s_waitcnt vmcnt(0) (forces wide loads; requests/row 3 or 5;
// FETCH ~ edges x requests x 64B, r11-verified). Stage words to LDS (word-major,
// stride 65) + logit inline. Online softmax via wave reductions; p broadcast via
// per-wave LDS (all-lane write while convergent). Phase B (lanes = channels):
// quad-accumulator FMA, broadcast word + shift unpack.
template <int OUT, int GXSW, int MINW>
__launch_bounds__(256, MINW)
__global__ void k_gat(const int* __restrict__ rowptr, const uint4* __restrict__ rec,
                      const unsigned* __restrict__ xl32, const float* __restrict__ xr,
                      const float* __restrict__ we, const float* __restrict__ ew,
                      const float* __restrict__ eb, const float* __restrict__ att,
                      const float* __restrict__ bias, float* __restrict__ h, int N) {
    constexpr int Q = OUT / 2;            // packed words per row
    constexpr int NW4 = GXSW / 4;         // dwordx4 loads per row (3 for 24, 5 for 36)
    __shared__ float sC[OUT * 4], sCb[OUT], sAtt[OUT], sB[OUT];
    __shared__ float sXB[4][OUT];         // xr row + sCb, per wave
    __shared__ unsigned sXL[4][Q * 65];   // staged fp16 words, word-major, stride 65
    __shared__ float sP[4][64];           // per-wave p broadcast (all-lane write)
    // fold edge MLP into GAT edge projection: C = we @ edge_w (OUT x 4), cb = we @ edge_b
    for (int t = threadIdx.x; t < OUT * 5; t += blockDim.x) {
        int k = t / 5, c = t - k * 5;
        float a = 0.f;
        if (c < 4) { for (int j = 0; j < 12; ++j) a += we[k * 12 + j] * ew[j * 4 + c]; sC[k * 4 + c] = a; }
        else       { for (int j = 0; j < 12; ++j) a += we[k * 12 + j] * eb[j];          sCb[k] = a; }
    }
    for (int t = threadIdx.x; t < OUT; t += blockDim.x) { sAtt[t] = att[t]; sB[t] = bias[t]; }
    __syncthreads();

    int wid = threadIdx.x >> 6, lane = threadIdx.x & 63;
    int n = blockIdx.x * 4 + wid;
    if (n >= N) return;   // wave-uniform; no syncthreads after this point

    if (lane < OUT) sXB[wid][lane] = xr[(size_t)n * OUT + lane] + sCb[lane];

    unsigned* myXL = &sXL[wid][0];
    float* myP  = &sP[wid][0];
    int rb = rowptr[n], re = rowptr[n + 1];

    float m = -INFINITY, den = 0.f, acc = 0.f;
    float as0 = 0.f, as1 = 0.f, as2 = 0.f, as3 = 0.f;   // raw-attr sums for self-loop mean

    for (int c0 = rb; c0 < re; c0 += 64) {
        int j = c0 + lane;
        float lg = -INFINITY;
        if (j < re) {
            uint4 r = rec[j];                   // coalesced 16B: {src, att_lo, att_hi, 0}
            int s = (int)r.x;
            float ax = h2f_lo(r.y), ay = h2f_hi(r.y);
            float az = h2f_lo(r.z), aw = h2f_hi(r.z);
            as0 += ax; as1 += ay; as2 += az; as3 += aw;

            const unsigned* rowp = xl32 + (size_t)s * GXSW;
            u32x4 w0, w1, w2, w3, w4;
            if constexpr (NW4 == 3) {
                asm volatile(
                    "global_load_dwordx4 %0, %3, off\n\t"
                    "global_load_dwordx4 %1, %3, off offset:16\n\t"
                    "global_load_dwordx4 %2, %3, off offset:32\n\t"
                    "s_waitcnt vmcnt(0)"
                    : "=&v"(w0), "=&v"(w1), "=&v"(w2)
                    : "v"(rowp));
            } else {
                asm volatile(
                    "global_load_dwordx4 %0, %5, off\n\t"
                    "global_load_dwordx4 %1, %5, off offset:16\n\t"
                    "global_load_dwordx4 %2, %5, off offset:32\n\t"
                    "global_load_dwordx4 %3, %5, off offset:48\n\t"
                    "global_load_dwordx4 %4, %5, off offset:64\n\t"
                    "s_waitcnt vmcnt(0)"
                    : "=&v"(w0), "=&v"(w1), "=&v"(w2), "=&v"(w3), "=&v"(w4)
                    : "v"(rowp));
            }
            lg = 0.f;
            #pragma unroll
            for (int q = 0; q < Q; ++q) {
                unsigned u = (q < 4) ? w0[q & 3] : (q < 8) ? w1[q & 3] :
                             (q < 12) ? w2[q & 3] : (q < 16) ? w3[q & 3] : w4[q & 3];
                myXL[q * 65 + lane] = u;
                float f0 = h2f_lo(u), f1 = h2f_hi(u);
                int k0 = 2 * q, k1 = 2 * q + 1;
                float c0v = sXB[wid][k0];
                c0v = fmaf(sC[k0 * 4 + 0], ax, c0v);
                c0v = fmaf(sC[k0 * 4 + 1], ay, c0v);
                c0v = fmaf(sC[k0 * 4 + 2], az, c0v);
                c0v = fmaf(sC[k0 * 4 + 3], aw, c0v);
                float m0 = f0 + c0v;
                float lr0 = (m0 > 0.f) ? m0 : 0.2f * m0;
                lg = fmaf(sAtt[k0], lr0, lg);
                float c1v = sXB[wid][k1];
                c1v = fmaf(sC[k1 * 4 + 0], ax, c1v);
                c1v = fmaf(sC[k1 * 4 + 1], ay, c1v);
                c1v = fmaf(sC[k1 * 4 + 2], az, c1v);
                c1v = fmaf(sC[k1 * 4 + 3], aw, c1v);
                float m1 = f1 + c1v;
                float lr1 = (m1 > 0.f) ? m1 : 0.2f * m1;
                lg = fmaf(sAtt[k1], lr1, lg);
            }
        }
        float cm = wred_max(lg);
        float nm = fmaxf(m, cm);
        float sc = __expf(m - nm);          // m=-inf on first chunk -> 0
        float p = (j < re) ? __expf(lg - nm) : 0.f;
        myP[lane] = p;                      // ALL 64 lanes write (convergent)
        float ps = wred_sum(p);
        den = den * sc + ps;
        m = nm;
        int cnt = min(64, re - c0);
        if (lane < OUT) {
            const int qq = lane >> 1;
            const int sh = (lane & 1) << 4;
            float a0 = 0.f, a1 = 0.f, a2 = 0.f, a3 = 0.f;
            int t = 0;
            for (; t + 3 < cnt; t += 4) {
                a0 = fmaf(myP[t],     h2f_u16((unsigned short)(myXL[qq * 65 + t]     >> sh)), a0);
                a1 = fmaf(myP[t + 1], h2f_u16((unsigned short)(myXL[qq * 65 + t + 1] >> sh)), a1);
                a2 = fmaf(myP[t + 2], h2f_u16((unsigned short)(myXL[qq * 65 + t + 2] >> sh)), a2);
                a3 = fmaf(myP[t + 3], h2f_u16((unsigned short)(myXL[qq * 65 + t + 3] >> sh)), a3);
            }
            for (; t < cnt; ++t)
                a0 = fmaf(myP[t], h2f_u16((unsigned short)(myXL[qq * 65 + t] >> sh)), a0);
            acc = fmaf(acc, sc, (a0 + a1) + (a2 + a3));
        }
    }

    // self-loop: attr = mean of incoming TRANSFORMED attrs (exact-0 if indeg==0)
    as0 = wred_sum(as0); as1 = wred_sum(as1); as2 = wred_sum(as2); as3 = wred_sum(as3);
    int cnt = re - rb;
    float inv = (cnt > 0) ? 1.f / (float)cnt : 0.f;
    float a0 = as0 * inv, a1 = as1 * inv, a2 = as2 * inv, a3 = as3 * inv;

    float xln = 0.f, contrib = 0.f;
    if (lane < OUT) {
        unsigned u = xl32[(size_t)n * GXSW + (lane >> 1)];
        xln = h2f_u16((unsigned short)(u >> ((lane & 1) << 4)));
        float dot = 0.f;
        dot = fmaf(sC[lane * 4 + 0], a0, dot);
        dot = fmaf(sC[lane * 4 + 1], a1, dot);
        dot = fmaf(sC[lane * 4 + 2], a2, dot);
        dot = fmaf(sC[lane * 4 + 3], a3, dot);
        // sXB = xr + sCb; when indeg==0 the transformed self attr is 0 -> remove sCb
        float mm = xln + sXB[wid][lane] + ((cnt > 0) ? dot : -sCb[lane]);
        float lr = (mm > 0.f) ? mm : 0.2f * mm;
        contrib = sAtt[lane] * lr;
    }
    float lgs = wred_sum(contrib);
    float nm = fmaxf(m, lgs);
    float sc = __expf(m - nm);
    float p = __expf(lgs - nm);
    den = den * sc + p;                      // den >= p > 0: no div-by-zero
    if (lane < OUT) {
        acc = acc * sc + p * xln;
        float v = acc / den + sB[lane];
        h[(size_t)n * OUT + lane] = (v > 0.f) ? v : 0.f;
    }
}

// ---------------- mean pool: one block per graph, batch is sorted ----------------
__global__ void k_pool(const float* __restrict__ h, const int* __restrict__ batch,
                       float* __restrict__ pmean, int N) {
    int g = blockIdx.x;
    int a = 0, b = N;
    while (a < b) { int mid = (a + b) >> 1; if (batch[mid] < g) a = mid + 1; else b = mid; }
    int lo = a;
    a = lo; b = N;
    while (a < b) { int mid = (a + b) >> 1; if (batch[mid] < g + 1) a = mid + 1; else b = mid; }
    int hi = a;
    int cnt = hi - lo;
    int wid = threadIdx.x >> 6, lane = threadIdx.x & 63;
    float acc = 0.f;
    if (lane < 36) {
        for (int n = lo + wid; n < hi; n += 4) acc += h[(size_t)n * 36 + lane];
    }
    __shared__ float s_acc[4][36];
    if (lane < 36) s_acc[wid][lane] = acc;
    __syncthreads();
    if (threadIdx.x < 36) {
        float v = s_acc[0][threadIdx.x] + s_acc[1][threadIdx.x] +
                  s_acc[2][threadIdx.x] + s_acc[3][threadIdx.x];
        float iv = (cnt > 0) ? 1.f / (float)cnt : 0.f;
        pmean[(size_t)g * 36 + threadIdx.x] = v * iv;
    }
}

// ---------------- final head ----------------
__global__ void k_final(const float* __restrict__ pmean,
                        const float* __restrict__ fw, const float* __restrict__ fb,
                        float* __restrict__ out, int G) {
    int t = blockIdx.x * blockDim.x + threadIdx.x;
    if (t >= G * 64) return;
    int g = t / 64, o = t - g * 64;
    float a = fb[o];
    #pragma unroll
    for (int k = 0; k < 36; ++k) a = fmaf(pmean[(size_t)g * 36 + k], fw[o * 36 + k], a);
    out[t] = a;
}

extern "C" void kernel_launch(void* const* d_in, const int* in_sizes, int n_in,
                              void* d_out, int out_size, void* d_ws, size_t ws_size,
                              hipStream_t stream) {
    const float* x      = (const float*)d_in[0];
    const int*   ei     = (const int*)d_in[1];
    const float* eattr  = (const float*)d_in[2];
    const int*   batch  = (const int*)d_in[3];
    const float* emb    = (const float*)d_in[4];
    const float* node_w = (const float*)d_in[5];
    const float* node_b = (const float*)d_in[6];
    const float* edge_w = (const float*)d_in[7];
    const float* edge_b = (const float*)d_in[8];
    const float* c1_wl  = (const float*)d_in[9];
    const float* c1_bl  = (const float*)d_in[10];
    const float* c1_wr  = (const float*)d_in[11];
    const float* c1_br  = (const float*)d_in[12];
    const float* c1_we  = (const float*)d_in[13];
    const float* c1_att = (const float*)d_in[14];
    const float* c1_bias= (const float*)d_in[15];
    const float* c2_wl  = (const float*)d_in[16];
    const float* c2_bl  = (const float*)d_in[17];
    const float* c2_wr  = (const float*)d_in[18];
    const float* c2_br  = (const float*)d_in[19];
    const float* c2_we  = (const float*)d_in[20];
    const float* c2_att = (const float*)d_in[21];
    const float* c2_bias= (const float*)d_in[22];
    const float* fin_w  = (const float*)d_in[23];
    const float* fin_b  = (const float*)d_in[24];
    float* out = (float*)d_out;

    const int N  = in_sizes[3];
    const int E2 = in_sizes[1] / 2;
    const int EU = in_sizes[2] / 4;
    const int XW = in_sizes[0] / N;
    const int NA = in_sizes[4] / 16;
    const int G  = out_size / 64;

    // workspace layout (4B units); rec 16B-aligned
    float* ws = (float*)d_ws;
    size_t off = 0;
    float*    h      = ws + off;              off += (size_t)N * 36;
    unsigned* xl32   = (unsigned*)(ws + off); off += (size_t)N * 20;   // 20-word (80B) max row stride
    float*    xr     = ws + off;              off += (size_t)N * 36;
    float*    pmean  = ws + off;              off += (size_t)G * 36;
    int*      rowptr = (int*)(ws + off);      off += (size_t)N + 1;
    int*      indeg  = (int*)(ws + off);      off += (size_t)N;
    int*      rank   = (int*)(ws + off);      off += (size_t)E2;
    int*      bsum   = (int*)(ws + off);      off += 64;
    off = (off + 3) & ~(size_t)3;             // 16B align
    uint4*    rec    = (uint4*)(ws + off);    off += (size_t)E2 * 4;
    size_t need = off * 4;

    if (ws_size < need) return;  // loud failure: output stays poisoned

    hipMemsetAsync(indeg, 0, (size_t)N * 4, stream);

    dim3 b(TPB);
    dim3 gN((N + TPB - 1) / TPB);
    dim3 gE((E2 + TPB - 1) / TPB);
    dim3 gW((N + 3) / 4);   // 4 waves per block, 1 wave per node
    int nb = (N + SCB * SCI - 1) / (SCB * SCI);

    k_node<<<gW, b, 0, stream>>>(x, emb, node_w, node_b, h, N, XW, NA);
    k_count<<<gE, b, 0, stream>>>(ei, indeg, rank, E2);
    k_scan_bsum<<<nb, SCB, 0, stream>>>(indeg, bsum, N);
    k_scan_final<<<nb, SCB, 0, stream>>>(indeg, bsum, rowptr, N, nb);
    k_scatter<<<gE, b, 0, stream>>>(ei, rowptr, rank, eattr, rec, E2, EU);

    // ---- layer 1 (24 -> 24): GXSW=12 (48B rows, 3 dwordx4), ~14.9KB LDS ----
    k_xform<24, 24, 12><<<gN, b, 0, stream>>>(h, c1_wl, c1_bl, c1_wr, c1_br, xl32, xr, N);
    k_gat<24, 12, 6><<<gW, b, 0, stream>>>(rowptr, rec, xl32, xr,
                                           c1_we, edge_w, edge_b, c1_att, c1_bias, h, N);

    // ---- layer 2 (24 -> 36): GXSW=20 (80B rows, 5 dwordx4), ~21.6KB LDS ----
    k_xform<24, 36, 20><<<gN, b, 0, stream>>>(h, c2_wl, c2_bl, c2_wr, c2_br, xl32, xr, N);
    k_gat<36, 20, 4><<<gW, b, 0, stream>>>(rowptr, rec, xl32, xr,
                                           c2_we, edge_w, edge_b, c2_att, c2_bias, h, N);

    // ---- pool + head ----
    k_pool<<<G, b, 0, stream>>>(h, batch, pmean, N);
    k_final<<<(G * 64 + TPB - 1) / TPB, b, 0, stream>>>(pmean, fin_w, fin_b, out, G);
}

// Round 13
// 529.133 us; speedup vs baseline: 13.2580x; 1.0641x over previous
//
#include <hip/hip_runtime.h>
#include <hip/hip_fp16.h>

#define TPB 256
#define SCB 256
#define SCI 16   // scan items per thread -> 4096 per block

typedef unsigned u32x4 __attribute__((ext_vector_type(4)));
typedef _Float16 half2_t __attribute__((ext_vector_type(2)));

__device__ __forceinline__ float wred_max(float v) {
    #pragma unroll
    for (int o = 32; o >= 1; o >>= 1) v = fmaxf(v, __shfl_xor(v, o));
    return v;
}
__device__ __forceinline__ float wred_sum(float v) {
    #pragma unroll
    for (int o = 32; o >= 1; o >>= 1) v += __shfl_xor(v, o);
    return v;
}
__device__ __forceinline__ float h2f_u16(unsigned short u) {
    __half_raw r; r.x = u; return __half2float(__half(r));
}
__device__ __forceinline__ float h2f_lo(unsigned u) { return h2f_u16((unsigned short)(u & 0xffffu)); }
__device__ __forceinline__ float h2f_hi(unsigned u) { return h2f_u16((unsigned short)(u >> 16)); }
__device__ __forceinline__ unsigned f2h_pack(float a, float b) {
    __half ha = __float2half(a), hb = __float2half(b);
    __half_raw ra = *(__half_raw*)&ha, rb = *(__half_raw*)&hb;
    return (unsigned)ra.x | ((unsigned)rb.x << 16);
}
__device__ __forceinline__ half2_t u2h2(unsigned u) { return __builtin_bit_cast(half2_t, u); }

#if defined(__has_builtin)
#if __has_builtin(__builtin_amdgcn_fdot2)
#define HAVE_FDOT2 1
#endif
#endif
__device__ __forceinline__ float fdot2f(half2_t a, half2_t b, float c) {
#ifdef HAVE_FDOT2
    return __builtin_amdgcn_fdot2(a, b, c, false);
#else
    return fmaf((float)a.x, (float)b.x, fmaf((float)a.y, (float)b.y, c));
#endif
}

// ---------------- node featurizer: wave per node (coalesced x reads) ----------------
__global__ void k_node(const float* __restrict__ x, const float* __restrict__ emb,
                       const float* __restrict__ nw, const float* __restrict__ nbv,
                       float* __restrict__ h, int N, int XW, int NA) {
    __shared__ float s_w[24 * 17];
    __shared__ float s_b[24];
    __shared__ float sF[4][20];
    for (int t = threadIdx.x; t < 24 * 17; t += blockDim.x) s_w[t] = nw[t];
    for (int t = threadIdx.x; t < 24; t += blockDim.x) s_b[t] = nbv[t];
    __syncthreads();
    int wid = threadIdx.x >> 6, lane = threadIdx.x & 63;
    int n = blockIdx.x * 4 + wid;
    if (n >= N) return;
    const float* row = x + (size_t)n * XW;
    float v0 = (lane < NA) ? row[lane] : -3.4e38f;
    float v1 = (lane + 64 < NA) ? row[lane + 64] : -3.4e38f;
    float bv; int bi;
    if (v1 > v0) { bv = v1; bi = lane + 64; } else { bv = v0; bi = lane; }
    #pragma unroll
    for (int o = 32; o >= 1; o >>= 1) {
        float ov = __shfl_xor(bv, o); int oi = __shfl_xor(bi, o);
        if (ov > bv || (ov == bv && oi < bi)) { bv = ov; bi = oi; }
    }
    if (lane < 16) sF[wid][lane] = emb[(size_t)bi * 16 + lane];
    if (lane == 16) sF[wid][16] = row[XW - 1];
    if (lane < 24) {
        float a = s_b[lane];
        #pragma unroll
        for (int j = 0; j < 17; ++j) a = fmaf(s_w[lane * 17 + j], sF[wid][j], a);
        h[(size_t)n * 24 + lane] = a;
    }
}

// ---------------- CSR build: count + per-edge rank (atomic returns rank) ----------------
__global__ void k_count(const int* __restrict__ ei, int* __restrict__ indeg,
                        int* __restrict__ rank, int E2) {
    int e = blockIdx.x * blockDim.x + threadIdx.x;
    if (e >= E2) return;
    rank[e] = atomicAdd(&indeg[ei[E2 + e]], 1);
}

__global__ void k_scan_bsum(const int* __restrict__ indeg, int* __restrict__ bsum, int N) {
    int base = blockIdx.x * SCB * SCI;
    int t = threadIdx.x;
    int s = 0;
    #pragma unroll
    for (int i = 0; i < SCI; ++i) {
        int idx = base + t * SCI + i;
        if (idx < N) s += indeg[idx];
    }
    #pragma unroll
    for (int o = 32; o >= 1; o >>= 1) s += __shfl_xor(s, o);
    __shared__ int red[SCB / 64];
    if ((t & 63) == 0) red[t >> 6] = s;
    __syncthreads();
    if (t == 0) {
        int tot = 0;
        for (int w = 0; w < SCB / 64; ++w) tot += red[w];
        bsum[blockIdx.x] = tot;
    }
}

__global__ void k_scan_final(const int* __restrict__ indeg, const int* __restrict__ bsum,
                             int* __restrict__ rowptr, int N, int nb) {
    __shared__ int s_t[SCB];
    __shared__ int s_boff;
    int base = blockIdx.x * SCB * SCI;
    int t = threadIdx.x;
    if (t == 0) {
        int off = 0;
        for (int i = 0; i < (int)blockIdx.x; ++i) off += bsum[i];
        s_boff = off;
        if (blockIdx.x == 0) {
            int tot = 0;
            for (int i = 0; i < nb; ++i) tot += bsum[i];
            rowptr[N] = tot;
        }
    }
    int loc[SCI]; int s = 0;
    #pragma unroll
    for (int i = 0; i < SCI; ++i) {
        int idx = base + t * SCI + i;
        int v = (idx < N) ? indeg[idx] : 0;
        loc[i] = s; s += v;
    }
    s_t[t] = s;
    __syncthreads();
    for (int o = 1; o < SCB; o <<= 1) {
        int v = (t >= o) ? s_t[t - o] : 0;
        __syncthreads();
        s_t[t] += v;
        __syncthreads();
    }
    int toff = ((t > 0) ? s_t[t - 1] : 0) + s_boff;
    #pragma unroll
    for (int i = 0; i < SCI; ++i) {
        int idx = base + t * SCI + i;
        if (idx < N) rowptr[idx] = toff + loc[i];
    }
}

// scatter edges into CSR as fused 16B records {src, att_lo, att_hi, 0}; NO atomics
__global__ void k_scatter(const int* __restrict__ ei, const int* __restrict__ rowptr,
                          const int* __restrict__ rank, const float* __restrict__ attr,
                          uint4* __restrict__ rec, int E2, int EU) {
    int e = blockIdx.x * blockDim.x + threadIdx.x;
    if (e >= E2) return;
    int s = ei[e];
    int d = ei[E2 + e];
    int pos = rowptr[d] + rank[e];
    int aid = (e < EU) ? e : e - EU;
    float4 av = *(const float4*)(attr + (size_t)aid * 4);
    rec[pos] = make_uint4((unsigned)s, f2h_pack(av.x, av.y), f2h_pack(av.z, av.w), 0u);
}

// ---------------- per-node transforms: xl -> packed fp16 words, xr -> fp32 ----------------
template <int IN, int OUT, int GXSW>
__global__ void k_xform(const float* __restrict__ h,
                        const float* __restrict__ wl, const float* __restrict__ bl,
                        const float* __restrict__ wr, const float* __restrict__ br,
                        unsigned* __restrict__ xl, float* __restrict__ xr, int N) {
    __shared__ float s_wl[OUT * IN], s_wr[OUT * IN], s_bl[OUT], s_br[OUT];
    for (int t = threadIdx.x; t < OUT * IN; t += blockDim.x) { s_wl[t] = wl[t]; s_wr[t] = wr[t]; }
    for (int t = threadIdx.x; t < OUT; t += blockDim.x) { s_bl[t] = bl[t]; s_br[t] = br[t]; }
    __syncthreads();
    int n = blockIdx.x * blockDim.x + threadIdx.x;
    if (n >= N) return;
    float f[IN];
    const float* hr = h + (size_t)n * IN;
    #pragma unroll
    for (int j = 0; j < IN; ++j) f[j] = hr[j];
    unsigned* xo = xl + (size_t)n * GXSW;
    #pragma unroll
    for (int q = 0; q < OUT / 2; ++q) {
        float a0 = s_bl[2 * q], a1 = s_bl[2 * q + 1];
        #pragma unroll
        for (int j = 0; j < IN; ++j) {
            a0 = fmaf(s_wl[(2 * q) * IN + j], f[j], a0);
            a1 = fmaf(s_wl[(2 * q + 1) * IN + j], f[j], a1);
        }
        xo[q] = f2h_pack(a0, a1);
    }
    float* xrr = xr + (size_t)n * OUT;
    #pragma unroll
    for (int k = 0; k < OUT; ++k) {
        float ar = s_br[k];
        #pragma unroll
        for (int j = 0; j < IN; ++j) ar = fmaf(s_wr[k * IN + j], f[j], ar);
        xrr[k] = ar;
    }
}

// ---------------- fused GATv2: packed-fp16 VALU path (v_pk_fma / v_dot2) ----------
// r12 established k_gat is VALU-bound (VALUBusy 95%, FETCH near-ideal). This version
// computes phase A per packed word with 4 pk_fma (attr proj) + pk_add + pk_mul/pk_max
// (leaky = max(m, 0.2m)) + one v_dot2_f32_f16 (f32 logit accumulator), and phase B
// with edge-PAIRED v_dot2 (v_perm_b32 builds the xl half2; p stored fp16) -- roughly
// halving VALU instructions vs the scalar-unpack path. Gather: r11-verified inline-asm
// wide loads. Online softmax (m, den) stays f32; self-loop final stays f32.
template <int OUT, int GXSW, int MINW>
__launch_bounds__(256, MINW)
__global__ void k_gat(const int* __restrict__ rowptr, const uint4* __restrict__ rec,
                      const unsigned* __restrict__ xl32, const float* __restrict__ xr,
                      const float* __restrict__ we, const float* __restrict__ ew,
                      const float* __restrict__ eb, const float* __restrict__ att,
                      const float* __restrict__ bias, float* __restrict__ h, int N) {
    constexpr int Q = OUT / 2;            // packed words per row
    constexpr int NW4 = GXSW / 4;         // dwordx4 loads per row (3 for 24, 5 for 36)
    __shared__ float sC[OUT * 4], sCb[OUT], sAtt[OUT], sB[OUT];
    __shared__ __attribute__((aligned(4))) _Float16 sC2h[OUT * 4];  // [q][c][par]
    __shared__ __attribute__((aligned(4))) _Float16 sAtt2h[OUT];    // [q][par]
    __shared__ half2_t sXB2[4][Q];        // (xr+cb) per wave, packed fp16
    __shared__ unsigned sXL[4][Q * 65];   // staged fp16 words, word-major, stride 65
    __shared__ __attribute__((aligned(4))) unsigned short sP16[4][64];  // p as fp16
    // fold edge MLP into GAT edge projection: C = we @ edge_w (OUT x 4), cb = we @ edge_b
    for (int t = threadIdx.x; t < OUT * 5; t += blockDim.x) {
        int k = t / 5, c = t - k * 5;
        float a = 0.f;
        if (c < 4) {
            for (int j = 0; j < 12; ++j) a += we[k * 12 + j] * ew[j * 4 + c];
            sC[k * 4 + c] = a;
            sC2h[(k >> 1) * 8 + c * 2 + (k & 1)] = (_Float16)a;
        } else {
            for (int j = 0; j < 12; ++j) a += we[k * 12 + j] * eb[j];
            sCb[k] = a;
        }
    }
    for (int t = threadIdx.x; t < OUT; t += blockDim.x) {
        sAtt[t] = att[t]; sAtt2h[t] = (_Float16)att[t]; sB[t] = bias[t];
    }
    __syncthreads();

    int wid = threadIdx.x >> 6, lane = threadIdx.x & 63;
    int n = blockIdx.x * 4 + wid;
    if (n >= N) return;   // wave-uniform; no syncthreads after this point

    if (lane < Q) {
        float2 v = *(const float2*)(xr + (size_t)n * OUT + 2 * lane);
        half2_t hv;
        hv.x = (_Float16)(v.x + sCb[2 * lane]);
        hv.y = (_Float16)(v.y + sCb[2 * lane + 1]);
        sXB2[wid][lane] = hv;
    }

    unsigned* myXL = &sXL[wid][0];
    unsigned short* myP16 = &sP16[wid][0];
    const half2_t* sC2 = (const half2_t*)sC2h;
    const half2_t* sAtt2 = (const half2_t*)sAtt2h;
    int rb = rowptr[n], re = rowptr[n + 1];

    half2_t k02; k02.x = (_Float16)0.2f; k02.y = (_Float16)0.2f;

    float m = -INFINITY, den = 0.f, acc = 0.f;
    float as0 = 0.f, as1 = 0.f, as2 = 0.f, as3 = 0.f;   // raw-attr sums for self-loop mean

    for (int c0 = rb; c0 < re; c0 += 64) {
        int j = c0 + lane;
        float lg = -INFINITY;
        if (j < re) {
            uint4 r = rec[j];                   // coalesced 16B: {src, att_lo, att_hi, 0}
            int s = (int)r.x;
            as0 += h2f_lo(r.y); as1 += h2f_hi(r.y);
            as2 += h2f_lo(r.z); as3 += h2f_hi(r.z);
            // broadcast each attr scalar to both halves (v_perm_b32)
            half2_t a0_2 = u2h2(__builtin_amdgcn_perm(r.y, r.y, 0x01000100u));
            half2_t a1_2 = u2h2(__builtin_amdgcn_perm(r.y, r.y, 0x03020302u));
            half2_t a2_2 = u2h2(__builtin_amdgcn_perm(r.z, r.z, 0x01000100u));
            half2_t a3_2 = u2h2(__builtin_amdgcn_perm(r.z, r.z, 0x03020302u));

            const unsigned* rowp = xl32 + (size_t)s * GXSW;
            u32x4 w0, w1, w2, w3, w4;
            if constexpr (NW4 == 3) {
                asm volatile(
                    "global_load_dwordx4 %0, %3, off\n\t"
                    "global_load_dwordx4 %1, %3, off offset:16\n\t"
                    "global_load_dwordx4 %2, %3, off offset:32\n\t"
                    "s_waitcnt vmcnt(0)"
                    : "=&v"(w0), "=&v"(w1), "=&v"(w2)
                    : "v"(rowp));
            } else {
                asm volatile(
                    "global_load_dwordx4 %0, %5, off\n\t"
                    "global_load_dwordx4 %1, %5, off offset:16\n\t"
                    "global_load_dwordx4 %2, %5, off offset:32\n\t"
                    "global_load_dwordx4 %3, %5, off offset:48\n\t"
                    "global_load_dwordx4 %4, %5, off offset:64\n\t"
                    "s_waitcnt vmcnt(0)"
                    : "=&v"(w0), "=&v"(w1), "=&v"(w2), "=&v"(w3), "=&v"(w4)
                    : "v"(rowp));
            }
            lg = 0.f;
            #pragma unroll
            for (int q = 0; q < Q; ++q) {
                unsigned u = (q < 4) ? w0[q & 3] : (q < 8) ? w1[q & 3] :
                             (q < 12) ? w2[q & 3] : (q < 16) ? w3[q & 3] : w4[q & 3];
                myXL[q * 65 + lane] = u;
                half2_t xl2 = u2h2(u);
                half2_t c2 = sXB2[wid][q];
                c2 = sC2[q * 4 + 0] * a0_2 + c2;   // v_pk_fma_f16
                c2 = sC2[q * 4 + 1] * a1_2 + c2;
                c2 = sC2[q * 4 + 2] * a2_2 + c2;
                c2 = sC2[q * 4 + 3] * a3_2 + c2;
                half2_t m2 = xl2 + c2;
                half2_t lr2 = __builtin_elementwise_max(m2, m2 * k02);  // leaky
                lg = fdot2f(sAtt2[q], lr2, lg);    // v_dot2_f32_f16, f32 acc
            }
        }
        float cm = wred_max(lg);
        float nm = fmaxf(m, cm);
        float sc = __expf(m - nm);          // m=-inf on first chunk -> 0
        float p = (j < re) ? __expf(lg - nm) : 0.f;
        myP16[lane] = __builtin_bit_cast(unsigned short, (_Float16)p);  // ALL lanes write
        float ps = wred_sum(p);
        den = den * sc + ps;
        m = nm;
        int cnt = min(64, re - c0);
        if (lane < OUT) {
            const int qq = lane >> 1;
            const unsigned sel = (lane & 1) ? 0x07060302u : 0x05040100u;
            const half2_t* pp = (const half2_t*)myP16;
            float a0 = 0.f, a1 = 0.f;
            int npair = cnt >> 1;
            int t2 = 0;
            for (; t2 + 1 < npair; t2 += 2) {
                unsigned u00 = myXL[qq * 65 + 2 * t2],     u01 = myXL[qq * 65 + 2 * t2 + 1];
                unsigned u10 = myXL[qq * 65 + 2 * t2 + 2], u11 = myXL[qq * 65 + 2 * t2 + 3];
                a0 = fdot2f(u2h2(__builtin_amdgcn_perm(u01, u00, sel)), pp[t2],     a0);
                a1 = fdot2f(u2h2(__builtin_amdgcn_perm(u11, u10, sel)), pp[t2 + 1], a1);
            }
            if (t2 < npair) {
                unsigned u00 = myXL[qq * 65 + 2 * t2], u01 = myXL[qq * 65 + 2 * t2 + 1];
                a0 = fdot2f(u2h2(__builtin_amdgcn_perm(u01, u00, sel)), pp[t2], a0);
            }
            if (cnt & 1) {
                int t = cnt - 1;
                unsigned u = myXL[qq * 65 + t];
                a0 = fmaf(h2f_u16(myP16[t]), h2f_u16((unsigned short)(u >> ((lane & 1) << 4))), a0);
            }
            acc = fmaf(acc, sc, a0 + a1);
        }
    }

    // self-loop: attr = mean of incoming TRANSFORMED attrs (exact-0 if indeg==0)
    as0 = wred_sum(as0); as1 = wred_sum(as1); as2 = wred_sum(as2); as3 = wred_sum(as3);
    int cnt = re - rb;
    float inv = (cnt > 0) ? 1.f / (float)cnt : 0.f;
    float a0 = as0 * inv, a1 = as1 * inv, a2 = as2 * inv, a3 = as3 * inv;

    float xln = 0.f, contrib = 0.f;
    if (lane < OUT) {
        unsigned u = xl32[(size_t)n * GXSW + (lane >> 1)];
        xln = h2f_u16((unsigned short)(u >> ((lane & 1) << 4)));
        float dot = 0.f;
        dot = fmaf(sC[lane * 4 + 0], a0, dot);
        dot = fmaf(sC[lane * 4 + 1], a1, dot);
        dot = fmaf(sC[lane * 4 + 2], a2, dot);
        dot = fmaf(sC[lane * 4 + 3], a3, dot);
        half2_t xb2 = sXB2[wid][lane >> 1];
        float xbf = (float)((lane & 1) ? xb2.y : xb2.x);
        // sXB2 = xr + sCb; when indeg==0 the transformed self attr is 0 -> remove sCb
        float mm = xln + xbf + ((cnt > 0) ? dot : -sCb[lane]);
        float lr = (mm > 0.f) ? mm : 0.2f * mm;
        contrib = sAtt[lane] * lr;
    }
    float lgs = wred_sum(contrib);
    float nm = fmaxf(m, lgs);
    float sc = __expf(m - nm);
    float p = __expf(lgs - nm);
    den = den * sc + p;                      // den >= p > 0: no div-by-zero
    if (lane < OUT) {
        acc = acc * sc + p * xln;
        float v = acc / den + sB[lane];
        h[(size_t)n * OUT + lane] = (v > 0.f) ? v : 0.f;
    }
}

// ---------------- mean pool: one block per graph, batch is sorted ----------------
__global__ void k_pool(const float* __restrict__ h, const int* __restrict__ batch,
                       float* __restrict__ pmean, int N) {
    int g = blockIdx.x;
    int a = 0, b = N;
    while (a < b) { int mid = (a + b) >> 1; if (batch[mid] < g) a = mid + 1; else b = mid; }
    int lo = a;
    a = lo; b = N;
    while (a < b) { int mid = (a + b) >> 1; if (batch[mid] < g + 1) a = mid + 1; else b = mid; }
    int hi = a;
    int cnt = hi - lo;
    int wid = threadIdx.x >> 6, lane = threadIdx.x & 63;
    float acc = 0.f;
    if (lane < 36) {
        for (int n = lo + wid; n < hi; n += 4) acc += h[(size_t)n * 36 + lane];
    }
    __shared__ float s_acc[4][36];
    if (lane < 36) s_acc[wid][lane] = acc;
    __syncthreads();
    if (threadIdx.x < 36) {
        float v = s_acc[0][threadIdx.x] + s_acc[1][threadIdx.x] +
                  s_acc[2][threadIdx.x] + s_acc[3][threadIdx.x];
        float iv = (cnt > 0) ? 1.f / (float)cnt : 0.f;
        pmean[(size_t)g * 36 + threadIdx.x] = v * iv;
    }
}

// ---------------- final head ----------------
__global__ void k_final(const float* __restrict__ pmean,
                        const float* __restrict__ fw, const float* __restrict__ fb,
                        float* __restrict__ out, int G) {
    int t = blockIdx.x * blockDim.x + threadIdx.x;
    if (t >= G * 64) return;
    int g = t / 64, o = t - g * 64;
    float a = fb[o];
    #pragma unroll
    for (int k = 0; k < 36; ++k) a = fmaf(pmean[(size_t)g * 36 + k], fw[o * 36 + k], a);
    out[t] = a;
}

extern "C" void kernel_launch(void* const* d_in, const int* in_sizes, int n_in,
                              void* d_out, int out_size, void* d_ws, size_t ws_size,
                              hipStream_t stream) {
    const float* x      = (const float*)d_in[0];
    const int*   ei     = (const int*)d_in[1];
    const float* eattr  = (const float*)d_in[2];
    const int*   batch  = (const int*)d_in[3];
    const float* emb    = (const float*)d_in[4];
    const float* node_w = (const float*)d_in[5];
    const float* node_b = (const float*)d_in[6];
    const float* edge_w = (const float*)d_in[7];
    const float* edge_b = (const float*)d_in[8];
    const float* c1_wl  = (const float*)d_in[9];
    const float* c1_bl  = (const float*)d_in[10];
    const float* c1_wr  = (const float*)d_in[11];
    const float* c1_br  = (const float*)d_in[12];
    const float* c1_we  = (const float*)d_in[13];
    const float* c1_att = (const float*)d_in[14];
    const float* c1_bias= (const float*)d_in[15];
    const float* c2_wl  = (const float*)d_in[16];
    const float* c2_bl  = (const float*)d_in[17];
    const float* c2_wr  = (const float*)d_in[18];
    const float* c2_br  = (const float*)d_in[19];
    const float* c2_we  = (const float*)d_in[20];
    const float* c2_att = (const float*)d_in[21];
    const float* c2_bias= (const float*)d_in[22];
    const float* fin_w  = (const float*)d_in[23];
    const float* fin_b  = (const float*)d_in[24];
    float* out = (float*)d_out;

    const int N  = in_sizes[3];
    const int E2 = in_sizes[1] / 2;
    const int EU = in_sizes[2] / 4;
    const int XW = in_sizes[0] / N;
    const int NA = in_sizes[4] / 16;
    const int G  = out_size / 64;

    // workspace layout (4B units); rec 16B-aligned
    float* ws = (float*)d_ws;
    size_t off = 0;
    float*    h      = ws + off;              off += (size_t)N * 36;
    unsigned* xl32   = (unsigned*)(ws + off); off += (size_t)N * 20;   // 20-word (80B) max row stride
    float*    xr     = ws + off;              off += (size_t)N * 36;
    float*    pmean  = ws + off;              off += (size_t)G * 36;
    int*      rowptr = (int*)(ws + off);      off += (size_t)N + 1;
    int*      indeg  = (int*)(ws + off);      off += (size_t)N;
    int*      rank   = (int*)(ws + off);      off += (size_t)E2;
    int*      bsum   = (int*)(ws + off);      off += 64;
    off = (off + 3) & ~(size_t)3;             // 16B align
    uint4*    rec    = (uint4*)(ws + off);    off += (size_t)E2 * 4;
    size_t need = off * 4;

    if (ws_size < need) return;  // loud failure: output stays poisoned

    hipMemsetAsync(indeg, 0, (size_t)N * 4, stream);

    dim3 b(TPB);
    dim3 gN((N + TPB - 1) / TPB);
    dim3 gE((E2 + TPB - 1) / TPB);
    dim3 gW((N + 3) / 4);   // 4 waves per block, 1 wave per node
    int nb = (N + SCB * SCI - 1) / (SCB * SCI);

    k_node<<<gW, b, 0, stream>>>(x, emb, node_w, node_b, h, N, XW, NA);
    k_count<<<gE, b, 0, stream>>>(ei, indeg, rank, E2);
    k_scan_bsum<<<nb, SCB, 0, stream>>>(indeg, bsum, N);
    k_scan_final<<<nb, SCB, 0, stream>>>(indeg, bsum, rowptr, N, nb);
    k_scatter<<<gE, b, 0, stream>>>(ei, rowptr, rank, eattr, rec, E2, EU);

    // ---- layer 1 (24 -> 24): GXSW=12 (48B rows, 3 dwordx4) ----
    k_xform<24, 24, 12><<<gN, b, 0, stream>>>(h, c1_wl, c1_bl, c1_wr, c1_br, xl32, xr, N);
    k_gat<24, 12, 6><<<gW, b, 0, stream>>>(rowptr, rec, xl32, xr,
                                           c1_we, edge_w, edge_b, c1_att, c1_bias, h, N);

    // ---- layer 2 (24 -> 36): GXSW=20 (80B rows, 5 dwordx4) ----
    k_xform<24, 36, 20><<<gN, b, 0, stream>>>(h, c2_wl, c2_bl, c2_wr, c2_br, xl32, xr, N);
    k_gat<36, 20, 4><<<gW, b, 0, stream>>>(rowptr, rec, xl32, xr,
                                           c2_we, edge_w, edge_b, c2_att, c2_bias, h, N);

    // ---- pool + head ----
    k_pool<<<G, b, 0, stream>>>(h, batch, pmean, N);
    k_final<<<(G * 64 + TPB - 1) / TPB, b, 0, stream>>>(pmean, fin_w, fin_b, out, G);
}